// Round 4
// baseline (728.447 us; speedup 1.0000x reference)
//
#include <hip/hip_runtime.h>
#include <hip/hip_bf16.h>
#include <math.h>

#define B_SZ    64
#define N_TOK   4096
#define D_FEAT  256
#define K_SLOTS 6
#define H_DIM   64
#define N_IT    3
#define CHUNKS  8
#define LNKV_BLOCKS 512
#define PREP_BLOCKS 8
#define TILES_PER_BLOCK 8   // 512 blocks * 8 tiles * 64 rows = 262144 rows

typedef __attribute__((ext_vector_type(8))) __bf16 bf16x8;
typedef __attribute__((ext_vector_type(4))) __bf16 bf16x4;
typedef __attribute__((ext_vector_type(4))) float  f32x4v;

__device__ __forceinline__ float wave_reduce_sum(float v) {
    #pragma unroll
    for (int off = 32; off > 0; off >>= 1) v += __shfl_xor(v, off, 64);
    return v;
}
__device__ __forceinline__ float bflo(unsigned u) { return __builtin_bit_cast(float, (unsigned)(u << 16)); }
__device__ __forceinline__ float bfhi(unsigned u) { return __builtin_bit_cast(float, (unsigned)(u & 0xffff0000u)); }

// ================= Launch 1: prep (blocks 0..7) + fused LN + MFMA GEMM -> kv ==========
__global__ __launch_bounds__(256, 2) void lnkv_fused(
    const float* __restrict__ feat, const float* __restrict__ g,
    const float* __restrict__ bta,
    const float* __restrict__ Wk, const float* __restrict__ Wv,
    __bf16* __restrict__ kv,
    const float* __restrict__ noise, const float* __restrict__ mu,
    const float* __restrict__ sigma, const float* __restrict__ Wq,
    const float* __restrict__ W_ih, const float* __restrict__ W_hh,
    const float* __restrict__ W1, const float* __restrict__ W2,
    float* __restrict__ slots, float* __restrict__ WqT,
    float* __restrict__ WihT, float* __restrict__ WhhT,
    float* __restrict__ W1T, float* __restrict__ W2T,
    int* __restrict__ cnt)
{
    if (blockIdx.x < PREP_BLOCKS) {
        if (blockIdx.x == 0 && threadIdx.x < N_IT * B_SZ) cnt[threadIdx.x] = 0;
        // small-weight prep: slots init + transposes (69632 elements, grid-stride)
        for (int i = blockIdx.x * 256 + threadIdx.x; i < 69632; i += PREP_BLOCKS * 256) {
            if (i < 24576) {
                slots[i] = mu[i & 63] + sigma[i & 63] * noise[i];
            } else if (i < 28672) {
                const int j = i - 24576;                 // WqT[j*64+h] = Wq[h*64+j]
                WqT[j] = Wq[(j & 63) * 64 + (j >> 6)];
            } else if (i < 40960) {
                const int j = i - 28672;                 // WihT[j*192+r] = W_ih[r*64+j]
                WihT[j] = W_ih[(j % 192) * 64 + (j / 192)];
            } else if (i < 53248) {
                const int j = i - 40960;
                WhhT[j] = W_hh[(j % 192) * 64 + (j / 192)];
            } else if (i < 61440) {
                const int j = i - 53248;                 // W1T[j*128+r] = W1[r*64+j]
                W1T[j] = W1[(j & 127) * 64 + (j >> 7)];
            } else {
                const int j = i - 61440;                 // W2T[c*64+h] = W2[h*128+c]
                W2T[j] = W2[(j & 63) * 128 + (j >> 6)];
            }
        }
        return;
    }

    __shared__ __align__(16) __bf16 A_lds[64][264];    // 33.8 KB
    __shared__ __align__(16) __bf16 C_lds[64][136];    // 17.4 KB

    const int bid = blockIdx.x - PREP_BLOCKS;
    const int t = threadIdx.x;
    const int lane = t & 63;
    const int w = t >> 6;
    const int m15 = lane & 15;
    const int q4 = lane >> 4;

    // W fragments in registers: wave w owns ct = 2w, 2w+1 (16 frags = 64 VGPRs).
    // frag value = Wkv[ct*16 + m15][q4*8 + ks*32 + j]  (Wkv = [Wk; Wv] rows)
    bf16x8 wf[2][8];
    #pragma unroll
    for (int c2 = 0; c2 < 2; ++c2) {
        const int row = (2 * w + c2) * 16 + m15;       // 0..127
        const float* srcw = (row < 64) ? &Wk[row * 256] : &Wv[(row - 64) * 256];
        #pragma unroll
        for (int ks = 0; ks < 8; ++ks) {
            const int col = q4 * 8 + ks * 32;
            const float4 a = *(const float4*)&srcw[col];
            const float4 c = *(const float4*)&srcw[col + 4];
            bf16x8 v;
            v[0] = (__bf16)a.x; v[1] = (__bf16)a.y; v[2] = (__bf16)a.z; v[3] = (__bf16)a.w;
            v[4] = (__bf16)c.x; v[5] = (__bf16)c.y; v[6] = (__bf16)c.z; v[7] = (__bf16)c.w;
            wf[c2][ks] = v;
        }
    }

    const float4 gg = *(const float4*)&g[lane * 4];
    const float4 bb = *(const float4*)&bta[lane * 4];

    float4 x[16];
    {   // prefetch tile 0 (wave-private rows)
        const size_t row0 = (size_t)bid * TILES_PER_BLOCK * 64 + w * 16;
        #pragma unroll
        for (int r = 0; r < 16; ++r)
            x[r] = *(const float4*)&feat[(row0 + r) * D_FEAT + lane * 4];
    }

    for (int tile = 0; tile < TILES_PER_BLOCK; ++tile) {
        const size_t tile_row0 = (size_t)bid * TILES_PER_BLOCK * 64 + (size_t)tile * 64;

        // ---- LN: batched stats, 32 independent reduction trees ----
        float s1[16], s2[16];
        #pragma unroll
        for (int r = 0; r < 16; ++r) {
            s1[r] = x[r].x + x[r].y + x[r].z + x[r].w;
            s2[r] = x[r].x * x[r].x + x[r].y * x[r].y + x[r].z * x[r].z + x[r].w * x[r].w;
        }
        #pragma unroll
        for (int off = 32; off > 0; off >>= 1) {
            #pragma unroll
            for (int r = 0; r < 16; ++r) {
                s1[r] += __shfl_xor(s1[r], off, 64);
                s2[r] += __shfl_xor(s2[r], off, 64);
            }
        }
        #pragma unroll
        for (int r = 0; r < 16; ++r) {
            const float m = s1[r] * (1.0f / 256.0f);
            const float inv = rsqrtf(s2[r] * (1.0f / 256.0f) - m * m + 1e-5f);
            bf16x4 y;
            y[0] = (__bf16)((x[r].x - m) * inv * gg.x + bb.x);
            y[1] = (__bf16)((x[r].y - m) * inv * gg.y + bb.y);
            y[2] = (__bf16)((x[r].z - m) * inv * gg.z + bb.z);
            y[3] = (__bf16)((x[r].w - m) * inv * gg.w + bb.w);
            *(bf16x4*)&A_lds[w * 16 + r][lane * 4] = y;
        }

        // prefetch next tile; latency hides under MFMA phase
        if (tile + 1 < TILES_PER_BLOCK) {
            const size_t row0 = tile_row0 + 64 + w * 16;
            #pragma unroll
            for (int r = 0; r < 16; ++r)
                x[r] = *(const float4*)&feat[(row0 + r) * D_FEAT + lane * 4];
        }

        __syncthreads();   // A_lds ready (also orders prev C_lds reads vs repack)

        // ---- MFMA: 4 m-tiles x 2 owned col-tiles, W from registers ----
        f32x4v acc[4][2];
        #pragma unroll
        for (int mt = 0; mt < 4; ++mt) {
            acc[mt][0] = (f32x4v){0.f, 0.f, 0.f, 0.f};
            acc[mt][1] = (f32x4v){0.f, 0.f, 0.f, 0.f};
        }
        #pragma unroll
        for (int ks = 0; ks < 8; ++ks) {
            #pragma unroll
            for (int mt = 0; mt < 4; ++mt) {
                const bf16x8 af = *(const bf16x8*)&A_lds[mt * 16 + m15][q4 * 8 + ks * 32];
                acc[mt][0] = __builtin_amdgcn_mfma_f32_16x16x32_bf16(af, wf[0][ks], acc[mt][0], 0, 0, 0);
                acc[mt][1] = __builtin_amdgcn_mfma_f32_16x16x32_bf16(af, wf[1][ks], acc[mt][1], 0, 0, 0);
            }
        }

        // repack: this wave's 32 cols, all 64 rows
        #pragma unroll
        for (int mt = 0; mt < 4; ++mt)
            #pragma unroll
            for (int c2 = 0; c2 < 2; ++c2)
                #pragma unroll
                for (int reg = 0; reg < 4; ++reg)
                    C_lds[mt * 16 + q4 * 4 + reg][(2 * w + c2) * 16 + m15] = (__bf16)acc[mt][c2][reg];

        __syncthreads();   // C_lds complete

        // coalesced bf16 store: wave w stores rows w*16..+15
        const int lr = w * 16 + (lane >> 2);
        const int seg = lane & 3;
        __bf16* dstg = kv + (tile_row0 + lr) * 128 + seg * 32;
        #pragma unroll
        for (int u = 0; u < 4; ++u) {
            const uint4 val = *(const uint4*)&C_lds[lr][seg * 32 + u * 8];
            *(uint4*)&dstg[u * 8] = val;
        }
    }
}

// ================= Launches 2-4: q-projection + attention chunk + last-block update ====
// 512 blocks: b = blk>>3 (batch), chunk = blk&7. No inter-block waiting: the 8th
// arrival for a batch (device-scope atomic counter) performs the slot update.
__global__ __launch_bounds__(256) void iter_kernel(
    const __bf16* __restrict__ kv,
    float* __restrict__ slots,
    float* __restrict__ U_part, float* __restrict__ S_part,
    int* __restrict__ cnt,
    const float* __restrict__ WqT,
    const float* __restrict__ WihT, const float* __restrict__ WhhT,
    const float* __restrict__ b_ih, const float* __restrict__ b_hh,
    const float* __restrict__ g_mlp, const float* __restrict__ b_mlp,
    const float* __restrict__ W1T, const float* __restrict__ b1,
    const float* __restrict__ W2T, const float* __restrict__ b2,
    const float* __restrict__ g_slot, const float* __restrict__ b_slot,
    float* __restrict__ out, int last)
{
    __shared__ float q_lds[K_SLOTS * 64];
    __shared__ __align__(16) __bf16 Vt[64][64];   // raw bf16, row n, col h
    __shared__ float p_lds[K_SLOTS][64];
    __shared__ float U_red[4][K_SLOTS][64];
    __shared__ float S_red[4][K_SLOTS];
    __shared__ int is_last_lds;

    const int t = threadIdx.x;
    const int blk = blockIdx.x;
    const int lane = t & 63;
    const int w = t >> 6;
    const int b = blk >> 3;
    const int chunk = blk & 7;
    const int n_loc = t >> 2, sub = t & 3;
    const int h = lane;

    // ---- q from current slots (wave-local; redundant across the 8 chunk blocks) ----
    for (int ks = w; ks < K_SLOTS; ks += 4) {
        const float xv = slots[(b * K_SLOTS + ks) * 64 + lane];
        const float s1 = wave_reduce_sum(xv);
        const float s2 = wave_reduce_sum(xv * xv);
        const float m = s1 * (1.0f / 64.0f);
        const float inv = rsqrtf(s2 * (1.0f / 64.0f) - m * m + 1e-5f);
        const float sv = (xv - m) * inv * g_slot[lane] + b_slot[lane];
        float acc = 0.f;
        #pragma unroll 8
        for (int j = 0; j < 64; ++j) acc += WqT[j * 64 + lane] * __shfl(sv, j, 64);
        q_lds[ks * 64 + lane] = acc * 0.125f;   // fold in 1/sqrt(H)
    }
    // (first barrier of the tile loop covers q_lds visibility)

    float Uacc[K_SLOTS] = {0, 0, 0, 0, 0, 0};
    float Sacc[K_SLOTS] = {0, 0, 0, 0, 0, 0};

    for (int tile = 0; tile < 8; ++tile) {
        __syncthreads();   // guard Vt/p_lds reuse (covers q_lds on tile 0)
        const size_t n0 = (size_t)b * N_TOK + (size_t)chunk * (N_TOK / CHUNKS) + tile * 64;

        // k loads: this thread's own phase-A operand (32 B, coalesced per row)
        const uint4* ksrc = (const uint4*)&kv[(n0 + n_loc) * 128 + sub * 16];
        const uint4 k0 = ksrc[0], k1 = ksrc[1];
        // v loads (raw staging)
        const uint4* vsrc = (const uint4*)&kv[(n0 + (t >> 2)) * 128 + 64 + (t & 3) * 16];
        const uint4 v0 = vsrc[0], v1 = vsrc[1];

        float kf[16];
        kf[0]  = bflo(k0.x); kf[1]  = bfhi(k0.x); kf[2]  = bflo(k0.y); kf[3]  = bfhi(k0.y);
        kf[4]  = bflo(k0.z); kf[5]  = bfhi(k0.z); kf[6]  = bflo(k0.w); kf[7]  = bfhi(k0.w);
        kf[8]  = bflo(k1.x); kf[9]  = bfhi(k1.x); kf[10] = bflo(k1.y); kf[11] = bfhi(k1.y);
        kf[12] = bflo(k1.z); kf[13] = bfhi(k1.z); kf[14] = bflo(k1.w); kf[15] = bfhi(k1.w);

        float part[K_SLOTS];
        #pragma unroll
        for (int k = 0; k < K_SLOTS; ++k) {
            const float4* q4p = (const float4*)&q_lds[k * 64 + sub * 16];
            const float4 qa = q4p[0], qb4 = q4p[1], qc = q4p[2], qd = q4p[3];
            part[k] = qa.x * kf[0]  + qa.y * kf[1]  + qa.z * kf[2]  + qa.w * kf[3]
                    + qb4.x * kf[4] + qb4.y * kf[5] + qb4.z * kf[6] + qb4.w * kf[7]
                    + qc.x * kf[8]  + qc.y * kf[9]  + qc.z * kf[10] + qc.w * kf[11]
                    + qd.x * kf[12] + qd.y * kf[13] + qd.z * kf[14] + qd.w * kf[15];
        }

        // stage V (raw bf16)
        *(uint4*)&Vt[t >> 2][(t & 3) * 16] = v0;
        *(uint4*)&Vt[t >> 2][(t & 3) * 16 + 8] = v1;

        #pragma unroll
        for (int k = 0; k < K_SLOTS; ++k) {
            part[k] += __shfl_xor(part[k], 1, 64);
            part[k] += __shfl_xor(part[k], 2, 64);
        }
        float mx = part[0];
        #pragma unroll
        for (int k = 1; k < K_SLOTS; ++k) mx = fmaxf(mx, part[k]);
        float e[K_SLOTS], ssum = 0.f;
        #pragma unroll
        for (int k = 0; k < K_SLOTS; ++k) { e[k] = __expf(part[k] - mx); ssum += e[k]; }
        const float rs = 1.0f / ssum;
        if (sub == 0) {
            #pragma unroll
            for (int k = 0; k < K_SLOTS; ++k) {
                const float p = e[k] * rs;
                p_lds[k][n_loc] = p;
                Sacc[k] += p;
            }
        }
        __syncthreads();

        // phase B: U[k][h] partial over this wave's 16 n
        float vf[16];
        #pragma unroll
        for (int i = 0; i < 16; ++i) vf[i] = (float)Vt[w * 16 + i][h];
        #pragma unroll
        for (int k = 0; k < K_SLOTS; ++k) {
            const float4* pp = (const float4*)&p_lds[k][w * 16];
            const float4 p0 = pp[0], p1 = pp[1], p2 = pp[2], p3 = pp[3];
            Uacc[k] += p0.x * vf[0]  + p0.y * vf[1]  + p0.z * vf[2]  + p0.w * vf[3]
                     + p1.x * vf[4]  + p1.y * vf[5]  + p1.z * vf[6]  + p1.w * vf[7]
                     + p2.x * vf[8]  + p2.y * vf[9]  + p2.z * vf[10] + p2.w * vf[11]
                     + p3.x * vf[12] + p3.y * vf[13] + p3.z * vf[14] + p3.w * vf[15];
        }
    }

    // ---- write this block's partials ----
    #pragma unroll
    for (int k = 0; k < K_SLOTS; ++k) U_red[w][k][h] = Uacc[k];
    #pragma unroll
    for (int k = 0; k < K_SLOTS; ++k) {
        const float s = wave_reduce_sum(Sacc[k]);
        if (lane == 0) S_red[w][k] = s;
    }
    __syncthreads();
    for (int idx = t; idx < K_SLOTS * 64; idx += 256) {
        const int k = idx >> 6, hh = idx & 63;
        const float s = U_red[0][k][hh] + U_red[1][k][hh] + U_red[2][k][hh] + U_red[3][k][hh];
        U_part[(((size_t)b * CHUNKS + chunk) * K_SLOTS + k) * 64 + hh] = s;
    }
    if (t < K_SLOTS) {
        const float s = S_red[0][t] + S_red[1][t] + S_red[2][t] + S_red[3][t];
        S_part[((size_t)b * CHUNKS + chunk) * K_SLOTS + t] = s;
    }

    // ---- arrival protocol: release writes, count, last block updates ----
    __threadfence();                       // release U_part/S_part (all threads)
    __syncthreads();                       // all fences done before the atomic
    if (t == 0) is_last_lds = (atomicAdd(&cnt[b], 1) == CHUNKS - 1) ? 1 : 0;
    __syncthreads();
    if (!is_last_lds) return;
    __threadfence();                       // acquire other blocks' partials

    // ---- update batch b: wave w handles slots ks = w, w+4 (wave-local, no LDS) ----
    for (int ks = w; ks < K_SLOTS; ks += 4) {
        const int bk = b * K_SLOTS + ks;
        float Us = 0.f, Ss = 0.f;
        #pragma unroll
        for (int c = 0; c < CHUNKS; ++c) {
            Us += U_part[(((size_t)b * CHUNKS + c) * K_SLOTS + ks) * 64 + lane];
            Ss += S_part[((size_t)b * CHUNKS + c) * K_SLOTS + ks];
        }
        const float u = Us / (Ss + 1e-8f);
        const float hp = slots[bk * 64 + lane];

        float ir = b_ih[lane], iz = b_ih[64 + lane], inn = b_ih[128 + lane];
        float hr = b_hh[lane], hz = b_hh[64 + lane], hn = b_hh[128 + lane];
        #pragma unroll 4
        for (int j = 0; j < 64; ++j) {
            const float xj = __shfl(u, j, 64);
            const float hj = __shfl(hp, j, 64);
            const float* wi = &WihT[j * 192];
            const float* wh = &WhhT[j * 192];
            ir += wi[lane] * xj; iz += wi[64 + lane] * xj; inn += wi[128 + lane] * xj;
            hr += wh[lane] * hj; hz += wh[64 + lane] * hj; hn += wh[128 + lane] * hj;
        }
        const float r = 1.0f / (1.0f + __expf(-(ir + hr)));
        const float z = 1.0f / (1.0f + __expf(-(iz + hz)));
        const float nn2 = tanhf(inn + r * hn);
        const float hnew = (1.0f - z) * nn2 + z * hp;

        const float s1 = wave_reduce_sum(hnew);
        const float s2 = wave_reduce_sum(hnew * hnew);
        const float m = s1 * (1.0f / 64.0f);
        const float inv = rsqrtf(s2 * (1.0f / 64.0f) - m * m + 1e-5f);
        const float mv = (hnew - m) * inv * g_mlp[lane] + b_mlp[lane];

        float a1 = b1[lane], a2 = b1[64 + lane];
        #pragma unroll 4
        for (int j = 0; j < 64; ++j) {
            const float mj = __shfl(mv, j, 64);
            a1 += W1T[j * 128 + lane] * mj;
            a2 += W1T[j * 128 + 64 + lane] * mj;
        }
        const float r1 = fmaxf(a1, 0.f), r2 = fmaxf(a2, 0.f);

        float o = b2[lane];
        #pragma unroll 4
        for (int c = 0; c < 64; ++c) {
            o += W2T[c * 64 + lane] * __shfl(r1, c, 64);
            o += W2T[(64 + c) * 64 + lane] * __shfl(r2, c, 64);
        }
        const float res = hnew + o;
        slots[bk * 64 + lane] = res;
        if (last) out[bk * 64 + lane] = res;
    }
}

extern "C" void kernel_launch(void* const* d_in, const int* in_sizes, int n_in,
                              void* d_out, int out_size, void* d_ws, size_t ws_size,
                              hipStream_t stream) {
    const float* feat      = (const float*)d_in[0];
    const float* noise     = (const float*)d_in[1];
    const float* mu        = (const float*)d_in[2];
    const float* sigma     = (const float*)d_in[3];
    const float* ln_feat_g = (const float*)d_in[4];
    const float* ln_feat_b = (const float*)d_in[5];
    const float* ln_slot_g = (const float*)d_in[6];
    const float* ln_slot_b = (const float*)d_in[7];
    const float* ln_mlp_g  = (const float*)d_in[8];
    const float* ln_mlp_b  = (const float*)d_in[9];
    const float* Wk        = (const float*)d_in[10];
    const float* Wv        = (const float*)d_in[11];
    const float* Wq        = (const float*)d_in[12];
    const float* W_ih      = (const float*)d_in[13];
    const float* W_hh      = (const float*)d_in[14];
    const float* b_ih      = (const float*)d_in[15];
    const float* b_hh      = (const float*)d_in[16];
    const float* W1        = (const float*)d_in[17];
    const float* b1        = (const float*)d_in[18];
    const float* W2        = (const float*)d_in[19];
    const float* b2        = (const float*)d_in[20];
    float* out = (float*)d_out;

    char* p = (char*)d_ws;
    __bf16* kv    = (__bf16*)p;                 p += (size_t)B_SZ * N_TOK * 128 * 2;  // 64 MB
    float* slots  = (float*)p;                  p += 24576 * 4;
    float* U_part = (float*)p;                  p += (size_t)B_SZ * CHUNKS * K_SLOTS * 64 * 4;
    float* S_part = (float*)p;                  p += (size_t)B_SZ * CHUNKS * K_SLOTS * 4;
    float* WqT    = (float*)p;                  p += 4096 * 4;
    float* WihT   = (float*)p;                  p += 12288 * 4;
    float* WhhT   = (float*)p;                  p += 12288 * 4;
    float* W1T    = (float*)p;                  p += 8192 * 4;
    float* W2T    = (float*)p;                  p += 8192 * 4;
    int*   cnt    = (int*)p;                    p += N_IT * B_SZ * 4;

    hipLaunchKernelGGL(lnkv_fused, dim3(LNKV_BLOCKS + PREP_BLOCKS), dim3(256), 0, stream,
                       feat, ln_feat_g, ln_feat_b, Wk, Wv, kv,
                       noise, mu, sigma, Wq, W_ih, W_hh, W1, W2,
                       slots, WqT, WihT, WhhT, W1T, W2T, cnt);

    for (int it = 0; it < N_IT; ++it) {
        hipLaunchKernelGGL(iter_kernel, dim3(LNKV_BLOCKS), dim3(256), 0, stream,
                           kv, slots, U_part, S_part, cnt + it * B_SZ,
                           WqT, WihT, WhhT, b_ih, b_hh,
                           ln_mlp_g, ln_mlp_b, W1T, b1, W2T, b2,
                           ln_slot_g, ln_slot_b, out, (it == N_IT - 1) ? 1 : 0);
    }
}

// Round 5
// 551.147 us; speedup vs baseline: 1.3217x; 1.3217x over previous
//
#include <hip/hip_runtime.h>
#include <hip/hip_bf16.h>
#include <math.h>

#define B_SZ    64
#define N_TOK   4096
#define D_FEAT  256
#define K_SLOTS 6
#define H_DIM   64
#define N_IT    3
#define CHUNKS  16
#define ATTN_TILES ((N_TOK / CHUNKS) / 64)   // 4
#define LNKV_BLOCKS 512
#define TILES_PER_BLOCK 8   // 512 blocks * 8 tiles * 64 rows = 262144 rows

typedef __attribute__((ext_vector_type(8))) __bf16 bf16x8;
typedef __attribute__((ext_vector_type(4))) __bf16 bf16x4;
typedef __attribute__((ext_vector_type(4))) float  f32x4v;

__device__ __forceinline__ float wave_reduce_sum(float v) {
    #pragma unroll
    for (int off = 32; off > 0; off >>= 1) v += __shfl_xor(v, off, 64);
    return v;
}
__device__ __forceinline__ float bflo(unsigned u) { return __builtin_bit_cast(float, (unsigned)(u << 16)); }
__device__ __forceinline__ float bfhi(unsigned u) { return __builtin_bit_cast(float, (unsigned)(u & 0xffff0000u)); }

// ================= prep: W->bf16 fragment order, slots init, transposed small weights ==========
__global__ __launch_bounds__(256) void prep_kernel(
    const float* __restrict__ Wk, const float* __restrict__ Wv,
    const float* __restrict__ noise, const float* __restrict__ mu,
    const float* __restrict__ sigma, const float* __restrict__ Wq,
    const float* __restrict__ W_ih, const float* __restrict__ W_hh,
    const float* __restrict__ W1, const float* __restrict__ W2,
    __bf16* __restrict__ Wfrag, float* __restrict__ slots,
    float* __restrict__ WqT, float* __restrict__ WihT, float* __restrict__ WhhT,
    float* __restrict__ W1T, float* __restrict__ W2T)
{
    const int tg = blockIdx.x * 256 + threadIdx.x;
    if (tg < 4096) {
        // W fragment order: [ct][ks][lane][j], value = Wkv[ct*16+(lane&15)][(lane>>4)*8+ks*32+j]
        const int chunk = tg >> 6, lane = tg & 63;
        const int ct = chunk >> 3, ks = chunk & 7;
        const int outr = ct * 16 + (lane & 15);
        const int dbase = (lane >> 4) * 8 + ks * 32;
        const float* srcw = (outr < 64) ? &Wk[outr * 256] : &Wv[(outr - 64) * 256];
        bf16x8 w8;
        #pragma unroll
        for (int j = 0; j < 8; ++j) w8[j] = (__bf16)srcw[dbase + j];
        *(bf16x8*)&Wfrag[(size_t)tg * 8] = w8;
    } else if (tg < 4096 + 24576) {
        const int i = tg - 4096;
        const int hh = i & 63;
        slots[i] = mu[hh] + sigma[hh] * noise[i];
    } else if (tg < 32768) {
        const int i = tg - 28672;                 // WqT[j*64+h] = Wq[h*64+j]
        WqT[i] = Wq[(i & 63) * 64 + (i >> 6)];
    } else if (tg < 45056) {
        const int i = tg - 32768;                 // WihT[j*192+r] = W_ih[r*64+j]
        WihT[i] = W_ih[(i % 192) * 64 + (i / 192)];
    } else if (tg < 57344) {
        const int i = tg - 45056;
        WhhT[i] = W_hh[(i % 192) * 64 + (i / 192)];
    } else if (tg < 65536) {
        const int i = tg - 57344;                 // W1T[j*128+r] = W1[r*64+j]
        W1T[i] = W1[(i & 127) * 64 + (i >> 7)];
    } else if (tg < 73728) {
        const int i = tg - 65536;                 // W2T[c*64+h] = W2[h*128+c]
        W2T[i] = W2[(i & 63) * 128 + (i >> 6)];
    }
}

// ================= Stage 1: fused LN + MFMA GEMM -> kv bf16 [row][128] ==========
__global__ __launch_bounds__(256, 2) void ln_kv_mfma(
    const float* __restrict__ feat, const float* __restrict__ g,
    const float* __restrict__ bta, const __bf16* __restrict__ Wfrag,
    __bf16* __restrict__ kv)
{
    __shared__ __align__(16) __bf16 A_lds[64][264];    // 33.8 KB
    __shared__ __align__(16) __bf16 C_lds[64][136];    // 17.4 KB

    const int t = threadIdx.x;
    const int lane = t & 63;
    const int w = t >> 6;
    const int m15 = lane & 15;
    const int q4 = lane >> 4;

    // W fragments in registers: wave w owns ct = 2w, 2w+1 (16 frags = 64 VGPRs)
    bf16x8 wf[2][8];
    #pragma unroll
    for (int c2 = 0; c2 < 2; ++c2)
        #pragma unroll
        for (int ks = 0; ks < 8; ++ks)
            wf[c2][ks] = *(const bf16x8*)&Wfrag[(size_t)(((2 * w + c2) * 8 + ks) * 64 + lane) * 8];

    const float4 gg = *(const float4*)&g[lane * 4];
    const float4 bb = *(const float4*)&bta[lane * 4];

    float4 x[16];
    {   // prefetch tile 0 (wave-private rows)
        const size_t row0 = (size_t)blockIdx.x * TILES_PER_BLOCK * 64 + w * 16;
        #pragma unroll
        for (int r = 0; r < 16; ++r)
            x[r] = *(const float4*)&feat[(row0 + r) * D_FEAT + lane * 4];
    }

    for (int tile = 0; tile < TILES_PER_BLOCK; ++tile) {
        const size_t tile_row0 = (size_t)blockIdx.x * TILES_PER_BLOCK * 64 + (size_t)tile * 64;

        // ---- LN: batched stats, 32 independent reduction trees ----
        float s1[16], s2[16];
        #pragma unroll
        for (int r = 0; r < 16; ++r) {
            s1[r] = x[r].x + x[r].y + x[r].z + x[r].w;
            s2[r] = x[r].x * x[r].x + x[r].y * x[r].y + x[r].z * x[r].z + x[r].w * x[r].w;
        }
        #pragma unroll
        for (int off = 32; off > 0; off >>= 1) {
            #pragma unroll
            for (int r = 0; r < 16; ++r) {
                s1[r] += __shfl_xor(s1[r], off, 64);
                s2[r] += __shfl_xor(s2[r], off, 64);
            }
        }
        #pragma unroll
        for (int r = 0; r < 16; ++r) {
            const float m = s1[r] * (1.0f / 256.0f);
            const float inv = rsqrtf(s2[r] * (1.0f / 256.0f) - m * m + 1e-5f);
            bf16x4 y;
            y[0] = (__bf16)((x[r].x - m) * inv * gg.x + bb.x);
            y[1] = (__bf16)((x[r].y - m) * inv * gg.y + bb.y);
            y[2] = (__bf16)((x[r].z - m) * inv * gg.z + bb.z);
            y[3] = (__bf16)((x[r].w - m) * inv * gg.w + bb.w);
            *(bf16x4*)&A_lds[w * 16 + r][lane * 4] = y;
        }

        // prefetch next tile; latency hides under MFMA phase
        if (tile + 1 < TILES_PER_BLOCK) {
            const size_t row0 = tile_row0 + 64 + w * 16;
            #pragma unroll
            for (int r = 0; r < 16; ++r)
                x[r] = *(const float4*)&feat[(row0 + r) * D_FEAT + lane * 4];
        }

        __syncthreads();   // A_lds ready (also orders prev C_lds reads vs repack)

        // ---- MFMA: 4 m-tiles x 2 owned col-tiles, W from registers ----
        f32x4v acc[4][2];
        #pragma unroll
        for (int mt = 0; mt < 4; ++mt) {
            acc[mt][0] = (f32x4v){0.f, 0.f, 0.f, 0.f};
            acc[mt][1] = (f32x4v){0.f, 0.f, 0.f, 0.f};
        }
        #pragma unroll
        for (int ks = 0; ks < 8; ++ks) {
            #pragma unroll
            for (int mt = 0; mt < 4; ++mt) {
                const bf16x8 af = *(const bf16x8*)&A_lds[mt * 16 + m15][q4 * 8 + ks * 32];
                acc[mt][0] = __builtin_amdgcn_mfma_f32_16x16x32_bf16(af, wf[0][ks], acc[mt][0], 0, 0, 0);
                acc[mt][1] = __builtin_amdgcn_mfma_f32_16x16x32_bf16(af, wf[1][ks], acc[mt][1], 0, 0, 0);
            }
        }

        // repack: this wave's 32 cols, all 64 rows
        #pragma unroll
        for (int mt = 0; mt < 4; ++mt)
            #pragma unroll
            for (int c2 = 0; c2 < 2; ++c2)
                #pragma unroll
                for (int reg = 0; reg < 4; ++reg)
                    C_lds[mt * 16 + q4 * 4 + reg][(2 * w + c2) * 16 + m15] = (__bf16)acc[mt][c2][reg];

        __syncthreads();   // C_lds complete

        // coalesced bf16 store: wave w stores rows w*16..+15
        const int lr = w * 16 + (lane >> 2);
        const int seg = lane & 3;
        __bf16* dstg = kv + (tile_row0 + lr) * 128 + seg * 32;
        #pragma unroll
        for (int u = 0; u < 4; ++u) {
            const uint4 val = *(const uint4*)&C_lds[lr][seg * 32 + u * 8];
            *(uint4*)&dstg[u * 8] = val;
        }
    }
}

// ================= initial q from slots ==========
__global__ __launch_bounds__(64) void slot_q0(
    const float* __restrict__ slots, const float* __restrict__ g,
    const float* __restrict__ bta, const float* __restrict__ WqT,
    float* __restrict__ qb)
{
    __shared__ float s_lds[64];
    const int bk = blockIdx.x, h = threadIdx.x;
    const float xv = slots[bk * 64 + h];
    const float s1 = wave_reduce_sum(xv);
    const float s2 = wave_reduce_sum(xv * xv);
    const float m = s1 * (1.0f / 64.0f);
    const float inv = rsqrtf(s2 * (1.0f / 64.0f) - m * m + 1e-5f);
    s_lds[h] = (xv - m) * inv * g[h] + bta[h];
    __syncthreads();
    float acc = 0.f;
    #pragma unroll 8
    for (int j = 0; j < 64; ++j) acc += WqT[j * 64 + h] * s_lds[j];
    qb[bk * 64 + h] = acc;
}

// ================= attention: 1024 blocks (4/CU, 16 waves/CU), cross-tile k/v prefetch ====
__global__ __launch_bounds__(256, 4) void attn_kernel(
    const float* __restrict__ qb, const __bf16* __restrict__ kv,
    float* __restrict__ U_part, float* __restrict__ S_part)
{
    __shared__ float q_lds[K_SLOTS * 64];
    __shared__ __align__(16) __bf16 Vt[64][64];   // raw bf16, row n, col h
    __shared__ float p_lds[K_SLOTS][64];
    __shared__ float U_red[4][K_SLOTS][64];
    __shared__ float S_red[4][K_SLOTS];

    const int t = threadIdx.x;
    const int b = blockIdx.y;
    const int chunk = blockIdx.x;
    const int lane = t & 63;
    const int w = t >> 6;
    const int n_loc = t >> 2, sub = t & 3;
    const int h = lane;

    // q pre-scaled by 1/sqrt(H) once
    for (int i = t; i < K_SLOTS * 64; i += 256) q_lds[i] = qb[b * K_SLOTS * 64 + i] * 0.125f;

    float Uacc[K_SLOTS] = {0, 0, 0, 0, 0, 0};
    float Sacc[K_SLOTS] = {0, 0, 0, 0, 0, 0};

    const size_t chunk_base = (size_t)b * N_TOK + (size_t)chunk * (N_TOK / CHUNKS);

    // prologue: tile-0 k/v loads into registers
    uint4 k0, k1, v0, v1;
    {
        const uint4* ksrc = (const uint4*)&kv[(chunk_base + n_loc) * 128 + sub * 16];
        k0 = ksrc[0]; k1 = ksrc[1];
        const uint4* vsrc = (const uint4*)&kv[(chunk_base + (t >> 2)) * 128 + 64 + (t & 3) * 16];
        v0 = vsrc[0]; v1 = vsrc[1];
    }

    for (int tile = 0; tile < ATTN_TILES; ++tile) {
        __syncthreads();   // guard Vt/p_lds reuse (covers q_lds on tile 0)

        // stage V for this tile (raw bf16)
        *(uint4*)&Vt[t >> 2][(t & 3) * 16] = v0;
        *(uint4*)&Vt[t >> 2][(t & 3) * 16 + 8] = v1;

        float kf[16];
        kf[0]  = bflo(k0.x); kf[1]  = bfhi(k0.x); kf[2]  = bflo(k0.y); kf[3]  = bfhi(k0.y);
        kf[4]  = bflo(k0.z); kf[5]  = bfhi(k0.z); kf[6]  = bflo(k0.w); kf[7]  = bfhi(k0.w);
        kf[8]  = bflo(k1.x); kf[9]  = bfhi(k1.x); kf[10] = bflo(k1.y); kf[11] = bfhi(k1.y);
        kf[12] = bflo(k1.z); kf[13] = bfhi(k1.z); kf[14] = bflo(k1.w); kf[15] = bfhi(k1.w);

        // prefetch next tile's k/v (latency hides under phase A + softmax + phase B)
        uint4 nk0, nk1, nv0, nv1;
        if (tile + 1 < ATTN_TILES) {
            const size_t n0n = chunk_base + (size_t)(tile + 1) * 64;
            const uint4* ksrc = (const uint4*)&kv[(n0n + n_loc) * 128 + sub * 16];
            nk0 = ksrc[0]; nk1 = ksrc[1];
            const uint4* vsrc = (const uint4*)&kv[(n0n + (t >> 2)) * 128 + 64 + (t & 3) * 16];
            nv0 = vsrc[0]; nv1 = vsrc[1];
        }

        // phase A: logits (4 subs x 16 h each)
        float part[K_SLOTS];
        #pragma unroll
        for (int k = 0; k < K_SLOTS; ++k) {
            const float4* q4p = (const float4*)&q_lds[k * 64 + sub * 16];
            const float4 qa = q4p[0], qb4 = q4p[1], qc = q4p[2], qd = q4p[3];
            part[k] = qa.x * kf[0]  + qa.y * kf[1]  + qa.z * kf[2]  + qa.w * kf[3]
                    + qb4.x * kf[4] + qb4.y * kf[5] + qb4.z * kf[6] + qb4.w * kf[7]
                    + qc.x * kf[8]  + qc.y * kf[9]  + qc.z * kf[10] + qc.w * kf[11]
                    + qd.x * kf[12] + qd.y * kf[13] + qd.z * kf[14] + qd.w * kf[15];
        }

        #pragma unroll
        for (int k = 0; k < K_SLOTS; ++k) {
            part[k] += __shfl_xor(part[k], 1, 64);
            part[k] += __shfl_xor(part[k], 2, 64);
        }
        float mx = part[0];
        #pragma unroll
        for (int k = 1; k < K_SLOTS; ++k) mx = fmaxf(mx, part[k]);
        float e[K_SLOTS], ssum = 0.f;
        #pragma unroll
        for (int k = 0; k < K_SLOTS; ++k) { e[k] = __expf(part[k] - mx); ssum += e[k]; }
        const float rs = 1.0f / ssum;
        if (sub == 0) {
            #pragma unroll
            for (int k = 0; k < K_SLOTS; ++k) {
                const float p = e[k] * rs;
                p_lds[k][n_loc] = p;
                Sacc[k] += p;
            }
        }
        __syncthreads();

        // phase B: U[k][h] partial over this wave's 16 n
        float vf[16];
        #pragma unroll
        for (int i = 0; i < 16; ++i) vf[i] = (float)Vt[w * 16 + i][h];
        #pragma unroll
        for (int k = 0; k < K_SLOTS; ++k) {
            const float4* pp = (const float4*)&p_lds[k][w * 16];
            const float4 p0 = pp[0], p1 = pp[1], p2 = pp[2], p3 = pp[3];
            Uacc[k] += p0.x * vf[0]  + p0.y * vf[1]  + p0.z * vf[2]  + p0.w * vf[3]
                     + p1.x * vf[4]  + p1.y * vf[5]  + p1.z * vf[6]  + p1.w * vf[7]
                     + p2.x * vf[8]  + p2.y * vf[9]  + p2.z * vf[10] + p2.w * vf[11]
                     + p3.x * vf[12] + p3.y * vf[13] + p3.z * vf[14] + p3.w * vf[15];
        }

        k0 = nk0; k1 = nk1; v0 = nv0; v1 = nv1;
    }

    #pragma unroll
    for (int k = 0; k < K_SLOTS; ++k) U_red[w][k][h] = Uacc[k];
    #pragma unroll
    for (int k = 0; k < K_SLOTS; ++k) {
        const float s = wave_reduce_sum(Sacc[k]);
        if (lane == 0) S_red[w][k] = s;
    }
    __syncthreads();
    for (int idx = t; idx < K_SLOTS * 64; idx += 256) {
        const int k = idx >> 6, hh = idx & 63;
        const float s = U_red[0][k][hh] + U_red[1][k][hh] + U_red[2][k][hh] + U_red[3][k][hh];
        U_part[(((size_t)b * CHUNKS + chunk) * K_SLOTS + k) * 64 + hh] = s;
    }
    if (t < K_SLOTS) {
        const float s = S_red[0][t] + S_red[1][t] + S_red[2][t] + S_red[3][t];
        S_part[((size_t)b * CHUNKS + chunk) * K_SLOTS + t] = s;
    }
}

// ================= reduce partials + GRU + LN + MLP + residual (+ next q) ==========
__global__ __launch_bounds__(64) void update_kernel(
    const float* __restrict__ U_part, const float* __restrict__ S_part,
    float* __restrict__ slots,
    const float* __restrict__ WihT, const float* __restrict__ WhhT,
    const float* __restrict__ b_ih, const float* __restrict__ b_hh,
    const float* __restrict__ g_mlp, const float* __restrict__ b_mlp,
    const float* __restrict__ W1T, const float* __restrict__ b1,
    const float* __restrict__ W2T, const float* __restrict__ b2,
    const float* __restrict__ g_slot, const float* __restrict__ b_slot,
    const float* __restrict__ WqT, float* __restrict__ qb,
    float* __restrict__ out, int last)
{
    __shared__ float x_lds[64], h_lds[64], m_lds[64], r_lds[128];
    const int bk = blockIdx.x, h = threadIdx.x;
    const int b = bk / K_SLOTS, k = bk % K_SLOTS;

    float Us = 0.f, Ss = 0.f;
    #pragma unroll
    for (int c = 0; c < CHUNKS; ++c)
        Us += U_part[(((size_t)b * CHUNKS + c) * K_SLOTS + k) * 64 + h];
    #pragma unroll
    for (int c = 0; c < CHUNKS; ++c)
        Ss += S_part[((size_t)b * CHUNKS + c) * K_SLOTS + k];

    const float u = Us / (Ss + 1e-8f);
    const float hp = slots[bk * 64 + h];
    x_lds[h] = u;
    h_lds[h] = hp;
    __syncthreads();

    float ir = b_ih[h], iz = b_ih[64 + h], inn = b_ih[128 + h];
    float hr = b_hh[h], hz = b_hh[64 + h], hn = b_hh[128 + h];
    #pragma unroll 4
    for (int j = 0; j < 64; ++j) {
        const float xj = x_lds[j], hj = h_lds[j];
        const float* wi = &WihT[j * 192];
        const float* wh = &WhhT[j * 192];
        ir += wi[h] * xj; iz += wi[64 + h] * xj; inn += wi[128 + h] * xj;
        hr += wh[h] * hj; hz += wh[64 + h] * hj; hn += wh[128 + h] * hj;
    }
    const float r = 1.0f / (1.0f + __expf(-(ir + hr)));
    const float z = 1.0f / (1.0f + __expf(-(iz + hz)));
    const float nn = tanhf(inn + r * hn);
    const float hnew = (1.0f - z) * nn + z * hp;

    const float s1 = wave_reduce_sum(hnew);
    const float s2 = wave_reduce_sum(hnew * hnew);
    const float m = s1 * (1.0f / 64.0f);
    const float inv = rsqrtf(s2 * (1.0f / 64.0f) - m * m + 1e-5f);
    m_lds[h] = (hnew - m) * inv * g_mlp[h] + b_mlp[h];
    __syncthreads();

    float a1 = b1[h], a2 = b1[64 + h];
    #pragma unroll 4
    for (int j = 0; j < 64; ++j) {
        const float mj = m_lds[j];
        a1 += W1T[j * 128 + h] * mj;
        a2 += W1T[j * 128 + 64 + h] * mj;
    }
    r_lds[h] = fmaxf(a1, 0.f);
    r_lds[64 + h] = fmaxf(a2, 0.f);
    __syncthreads();

    float o = b2[h];
    #pragma unroll 4
    for (int c = 0; c < 128; ++c) o += W2T[c * 64 + h] * r_lds[c];

    const float res = hnew + o;
    slots[bk * 64 + h] = res;
    if (last) {
        out[bk * 64 + h] = res;
    } else {
        // fused q for next iteration
        const float t1 = wave_reduce_sum(res);
        const float t2 = wave_reduce_sum(res * res);
        const float mm = t1 * (1.0f / 64.0f);
        const float ii = rsqrtf(t2 * (1.0f / 64.0f) - mm * mm + 1e-5f);
        m_lds[h] = (res - mm) * ii * g_slot[h] + b_slot[h];
        __syncthreads();
        float qv = 0.f;
        #pragma unroll 8
        for (int j = 0; j < 64; ++j) qv += WqT[j * 64 + h] * m_lds[j];
        qb[bk * 64 + h] = qv;
    }
}

extern "C" void kernel_launch(void* const* d_in, const int* in_sizes, int n_in,
                              void* d_out, int out_size, void* d_ws, size_t ws_size,
                              hipStream_t stream) {
    const float* feat      = (const float*)d_in[0];
    const float* noise     = (const float*)d_in[1];
    const float* mu        = (const float*)d_in[2];
    const float* sigma     = (const float*)d_in[3];
    const float* ln_feat_g = (const float*)d_in[4];
    const float* ln_feat_b = (const float*)d_in[5];
    const float* ln_slot_g = (const float*)d_in[6];
    const float* ln_slot_b = (const float*)d_in[7];
    const float* ln_mlp_g  = (const float*)d_in[8];
    const float* ln_mlp_b  = (const float*)d_in[9];
    const float* Wk        = (const float*)d_in[10];
    const float* Wv        = (const float*)d_in[11];
    const float* Wq        = (const float*)d_in[12];
    const float* W_ih      = (const float*)d_in[13];
    const float* W_hh      = (const float*)d_in[14];
    const float* b_ih      = (const float*)d_in[15];
    const float* b_hh      = (const float*)d_in[16];
    const float* W1        = (const float*)d_in[17];
    const float* b1        = (const float*)d_in[18];
    const float* W2        = (const float*)d_in[19];
    const float* b2        = (const float*)d_in[20];
    float* out = (float*)d_out;

    char* p = (char*)d_ws;
    __bf16* kv    = (__bf16*)p;                 p += (size_t)B_SZ * N_TOK * 128 * 2;  // 64 MB
    __bf16* Wfrag = (__bf16*)p;                 p += 32768 * 2;
    float* slots  = (float*)p;                  p += 24576 * 4;
    float* qb     = (float*)p;                  p += 24576 * 4;
    float* U_part = (float*)p;                  p += (size_t)B_SZ * CHUNKS * K_SLOTS * 64 * 4;
    float* S_part = (float*)p;                  p += (size_t)B_SZ * CHUNKS * K_SLOTS * 4;
    float* WqT    = (float*)p;                  p += 4096 * 4;
    float* WihT   = (float*)p;                  p += 12288 * 4;
    float* WhhT   = (float*)p;                  p += 12288 * 4;
    float* W1T    = (float*)p;                  p += 8192 * 4;
    float* W2T    = (float*)p;                  p += 8192 * 4;

    hipLaunchKernelGGL(prep_kernel, dim3(288), dim3(256), 0, stream,
                       Wk, Wv, noise, mu, sigma, Wq, W_ih, W_hh, W1, W2,
                       Wfrag, slots, WqT, WihT, WhhT, W1T, W2T);
    hipLaunchKernelGGL(ln_kv_mfma, dim3(LNKV_BLOCKS), dim3(256), 0, stream,
                       feat, ln_feat_g, ln_feat_b, Wfrag, kv);
    hipLaunchKernelGGL(slot_q0, dim3(384), dim3(64), 0, stream,
                       slots, ln_slot_g, ln_slot_b, WqT, qb);
    for (int it = 0; it < N_IT; ++it) {
        hipLaunchKernelGGL(attn_kernel, dim3(CHUNKS, B_SZ), dim3(256), 0, stream,
                           qb, kv, U_part, S_part);
        hipLaunchKernelGGL(update_kernel, dim3(384), dim3(64), 0, stream,
                           U_part, S_part, slots, WihT, WhhT, b_ih, b_hh,
                           ln_mlp_g, ln_mlp_b, W1T, b1, W2T, b2,
                           ln_slot_g, ln_slot_b, WqT, qb,
                           out, (it == N_IT - 1) ? 1 : 0);
    }
}

// Round 6
// 502.006 us; speedup vs baseline: 1.4511x; 1.0979x over previous
//
#include <hip/hip_runtime.h>
#include <hip/hip_bf16.h>
#include <math.h>

#define B_SZ    64
#define N_TOK   4096
#define D_FEAT  256
#define K_SLOTS 6
#define H_DIM   64
#define N_IT    3
#define CHUNKS  16
#define ATTN_TILES ((N_TOK / CHUNKS) / 64)   // 4
#define LNKV_BLOCKS 512
#define TILES_PER_BLOCK 8   // 512 blocks * 8 tiles * 64 rows = 262144 rows

typedef __attribute__((ext_vector_type(8))) __bf16 bf16x8;
typedef __attribute__((ext_vector_type(4))) __bf16 bf16x4;
typedef __attribute__((ext_vector_type(4))) float  f32x4v;

__device__ __forceinline__ float wave_reduce_sum(float v) {
    #pragma unroll
    for (int off = 32; off > 0; off >>= 1) v += __shfl_xor(v, off, 64);
    return v;
}
__device__ __forceinline__ float bflo(unsigned u) { return __builtin_bit_cast(float, (unsigned)(u << 16)); }
__device__ __forceinline__ float bfhi(unsigned u) { return __builtin_bit_cast(float, (unsigned)(u & 0xffff0000u)); }

// ================= prep: W->bf16 fragment order, slots init, transposed small weights ==========
__global__ __launch_bounds__(256) void prep_kernel(
    const float* __restrict__ Wk, const float* __restrict__ Wv,
    const float* __restrict__ noise, const float* __restrict__ mu,
    const float* __restrict__ sigma, const float* __restrict__ Wq,
    const float* __restrict__ W_ih, const float* __restrict__ W_hh,
    const float* __restrict__ W1, const float* __restrict__ W2,
    __bf16* __restrict__ Wfrag, float* __restrict__ slots,
    float* __restrict__ WqT, float* __restrict__ WihT, float* __restrict__ WhhT,
    float* __restrict__ W1T, float* __restrict__ W2T)
{
    const int tg = blockIdx.x * 256 + threadIdx.x;
    if (tg < 4096) {
        // W fragment order: [ct][ks][lane][j], value = Wkv[ct*16+(lane&15)][(lane>>4)*8+ks*32+j]
        const int chunk = tg >> 6, lane = tg & 63;
        const int ct = chunk >> 3, ks = chunk & 7;
        const int outr = ct * 16 + (lane & 15);
        const int dbase = (lane >> 4) * 8 + ks * 32;
        const float* srcw = (outr < 64) ? &Wk[outr * 256] : &Wv[(outr - 64) * 256];
        bf16x8 w8;
        #pragma unroll
        for (int j = 0; j < 8; ++j) w8[j] = (__bf16)srcw[dbase + j];
        *(bf16x8*)&Wfrag[(size_t)tg * 8] = w8;
    } else if (tg < 4096 + 24576) {
        const int i = tg - 4096;
        const int hh = i & 63;
        slots[i] = mu[hh] + sigma[hh] * noise[i];
    } else if (tg < 32768) {
        const int i = tg - 28672;                 // WqT[j*64+h] = Wq[h*64+j]
        WqT[i] = Wq[(i & 63) * 64 + (i >> 6)];
    } else if (tg < 45056) {
        const int i = tg - 32768;                 // WihT[j*192+r] = W_ih[r*64+j]
        WihT[i] = W_ih[(i % 192) * 64 + (i / 192)];
    } else if (tg < 57344) {
        const int i = tg - 45056;
        WhhT[i] = W_hh[(i % 192) * 64 + (i / 192)];
    } else if (tg < 65536) {
        const int i = tg - 57344;                 // W1T[j*128+r] = W1[r*64+j]
        W1T[i] = W1[(i & 127) * 64 + (i >> 7)];
    } else if (tg < 73728) {
        const int i = tg - 65536;                 // W2T[c*64+h] = W2[h*128+c]
        W2T[i] = W2[(i & 63) * 128 + (i >> 6)];
    }
}

// ================= Stage 1: fused LN + MFMA GEMM -> kv bf16 [row][128] ==========
__global__ __launch_bounds__(256, 2) void ln_kv_mfma(
    const float* __restrict__ feat, const float* __restrict__ g,
    const float* __restrict__ bta, const __bf16* __restrict__ Wfrag,
    __bf16* __restrict__ kv)
{
    __shared__ __align__(16) __bf16 A_lds[64][264];    // 33.8 KB
    __shared__ __align__(16) __bf16 C_lds[64][136];    // 17.4 KB

    const int t = threadIdx.x;
    const int lane = t & 63;
    const int w = t >> 6;
    const int m15 = lane & 15;
    const int q4 = lane >> 4;

    // W fragments in registers: wave w owns ct = 2w, 2w+1 (16 frags = 64 VGPRs)
    bf16x8 wf[2][8];
    #pragma unroll
    for (int c2 = 0; c2 < 2; ++c2)
        #pragma unroll
        for (int ks = 0; ks < 8; ++ks)
            wf[c2][ks] = *(const bf16x8*)&Wfrag[(size_t)(((2 * w + c2) * 8 + ks) * 64 + lane) * 8];

    const float4 gg = *(const float4*)&g[lane * 4];
    const float4 bb = *(const float4*)&bta[lane * 4];

    float4 x[16];
    {   // prefetch tile 0 (wave-private rows)
        const size_t row0 = (size_t)blockIdx.x * TILES_PER_BLOCK * 64 + w * 16;
        #pragma unroll
        for (int r = 0; r < 16; ++r)
            x[r] = *(const float4*)&feat[(row0 + r) * D_FEAT + lane * 4];
    }

    for (int tile = 0; tile < TILES_PER_BLOCK; ++tile) {
        const size_t tile_row0 = (size_t)blockIdx.x * TILES_PER_BLOCK * 64 + (size_t)tile * 64;

        // ---- LN: batched stats, 32 independent reduction trees ----
        float s1[16], s2[16];
        #pragma unroll
        for (int r = 0; r < 16; ++r) {
            s1[r] = x[r].x + x[r].y + x[r].z + x[r].w;
            s2[r] = x[r].x * x[r].x + x[r].y * x[r].y + x[r].z * x[r].z + x[r].w * x[r].w;
        }
        #pragma unroll
        for (int off = 32; off > 0; off >>= 1) {
            #pragma unroll
            for (int r = 0; r < 16; ++r) {
                s1[r] += __shfl_xor(s1[r], off, 64);
                s2[r] += __shfl_xor(s2[r], off, 64);
            }
        }
        #pragma unroll
        for (int r = 0; r < 16; ++r) {
            const float m = s1[r] * (1.0f / 256.0f);
            const float inv = rsqrtf(s2[r] * (1.0f / 256.0f) - m * m + 1e-5f);
            bf16x4 y;
            y[0] = (__bf16)((x[r].x - m) * inv * gg.x + bb.x);
            y[1] = (__bf16)((x[r].y - m) * inv * gg.y + bb.y);
            y[2] = (__bf16)((x[r].z - m) * inv * gg.z + bb.z);
            y[3] = (__bf16)((x[r].w - m) * inv * gg.w + bb.w);
            *(bf16x4*)&A_lds[w * 16 + r][lane * 4] = y;
        }

        // prefetch next tile; latency hides under MFMA phase
        if (tile + 1 < TILES_PER_BLOCK) {
            const size_t row0 = tile_row0 + 64 + w * 16;
            #pragma unroll
            for (int r = 0; r < 16; ++r)
                x[r] = *(const float4*)&feat[(row0 + r) * D_FEAT + lane * 4];
        }

        __syncthreads();   // A_lds ready (also orders prev C_lds reads vs repack)

        // ---- MFMA: 4 m-tiles x 2 owned col-tiles, W from registers ----
        f32x4v acc[4][2];
        #pragma unroll
        for (int mt = 0; mt < 4; ++mt) {
            acc[mt][0] = (f32x4v){0.f, 0.f, 0.f, 0.f};
            acc[mt][1] = (f32x4v){0.f, 0.f, 0.f, 0.f};
        }
        #pragma unroll
        for (int ks = 0; ks < 8; ++ks) {
            #pragma unroll
            for (int mt = 0; mt < 4; ++mt) {
                const bf16x8 af = *(const bf16x8*)&A_lds[mt * 16 + m15][q4 * 8 + ks * 32];
                acc[mt][0] = __builtin_amdgcn_mfma_f32_16x16x32_bf16(af, wf[0][ks], acc[mt][0], 0, 0, 0);
                acc[mt][1] = __builtin_amdgcn_mfma_f32_16x16x32_bf16(af, wf[1][ks], acc[mt][1], 0, 0, 0);
            }
        }

        // repack: this wave's 32 cols, all 64 rows
        #pragma unroll
        for (int mt = 0; mt < 4; ++mt)
            #pragma unroll
            for (int c2 = 0; c2 < 2; ++c2)
                #pragma unroll
                for (int reg = 0; reg < 4; ++reg)
                    C_lds[mt * 16 + q4 * 4 + reg][(2 * w + c2) * 16 + m15] = (__bf16)acc[mt][c2][reg];

        __syncthreads();   // C_lds complete

        // coalesced bf16 store: wave w stores rows w*16..+15
        const int lr = w * 16 + (lane >> 2);
        const int seg = lane & 3;
        __bf16* dstg = kv + (tile_row0 + lr) * 128 + seg * 32;
        #pragma unroll
        for (int u = 0; u < 4; ++u) {
            const uint4 val = *(const uint4*)&C_lds[lr][seg * 32 + u * 8];
            *(uint4*)&dstg[u * 8] = val;
        }
    }
}

// ================= initial q from slots ==========
__global__ __launch_bounds__(64) void slot_q0(
    const float* __restrict__ slots, const float* __restrict__ g,
    const float* __restrict__ bta, const float* __restrict__ WqT,
    float* __restrict__ qb)
{
    __shared__ float s_lds[64];
    const int bk = blockIdx.x, h = threadIdx.x;
    const float xv = slots[bk * 64 + h];
    const float s1 = wave_reduce_sum(xv);
    const float s2 = wave_reduce_sum(xv * xv);
    const float m = s1 * (1.0f / 64.0f);
    const float inv = rsqrtf(s2 * (1.0f / 64.0f) - m * m + 1e-5f);
    s_lds[h] = (xv - m) * inv * g[h] + bta[h];
    __syncthreads();
    float acc = 0.f;
    #pragma unroll 8
    for (int j = 0; j < 64; ++j) acc += WqT[j * 64 + h] * s_lds[j];
    qb[bk * 64 + h] = acc;
}

// ================= attention: 1024 blocks (4/CU, 16 waves/CU), cross-tile k/v prefetch ====
__global__ __launch_bounds__(256, 4) void attn_kernel(
    const float* __restrict__ qb, const __bf16* __restrict__ kv,
    float* __restrict__ U_part, float* __restrict__ S_part)
{
    __shared__ float q_lds[K_SLOTS * 64];
    __shared__ __align__(16) __bf16 Vt[64][64];   // raw bf16, row n, col h
    __shared__ float p_lds[K_SLOTS][64];
    __shared__ float U_red[4][K_SLOTS][64];
    __shared__ float S_red[4][K_SLOTS];

    const int t = threadIdx.x;
    const int b = blockIdx.y;
    const int chunk = blockIdx.x;
    const int lane = t & 63;
    const int w = t >> 6;
    const int n_loc = t >> 2, sub = t & 3;
    const int h = lane;

    // q pre-scaled by 1/sqrt(H) once
    for (int i = t; i < K_SLOTS * 64; i += 256) q_lds[i] = qb[b * K_SLOTS * 64 + i] * 0.125f;

    float Uacc[K_SLOTS] = {0, 0, 0, 0, 0, 0};
    float Sacc[K_SLOTS] = {0, 0, 0, 0, 0, 0};

    const size_t chunk_base = (size_t)b * N_TOK + (size_t)chunk * (N_TOK / CHUNKS);

    // prologue: tile-0 k/v loads into registers
    uint4 k0, k1, v0, v1;
    {
        const uint4* ksrc = (const uint4*)&kv[(chunk_base + n_loc) * 128 + sub * 16];
        k0 = ksrc[0]; k1 = ksrc[1];
        const uint4* vsrc = (const uint4*)&kv[(chunk_base + (t >> 2)) * 128 + 64 + (t & 3) * 16];
        v0 = vsrc[0]; v1 = vsrc[1];
    }

    for (int tile = 0; tile < ATTN_TILES; ++tile) {
        __syncthreads();   // guard Vt/p_lds reuse (covers q_lds on tile 0)

        // stage V for this tile (raw bf16)
        *(uint4*)&Vt[t >> 2][(t & 3) * 16] = v0;
        *(uint4*)&Vt[t >> 2][(t & 3) * 16 + 8] = v1;

        float kf[16];
        kf[0]  = bflo(k0.x); kf[1]  = bfhi(k0.x); kf[2]  = bflo(k0.y); kf[3]  = bfhi(k0.y);
        kf[4]  = bflo(k0.z); kf[5]  = bfhi(k0.z); kf[6]  = bflo(k0.w); kf[7]  = bfhi(k0.w);
        kf[8]  = bflo(k1.x); kf[9]  = bfhi(k1.x); kf[10] = bflo(k1.y); kf[11] = bfhi(k1.y);
        kf[12] = bflo(k1.z); kf[13] = bfhi(k1.z); kf[14] = bflo(k1.w); kf[15] = bfhi(k1.w);

        // prefetch next tile's k/v (latency hides under phase A + softmax + phase B)
        uint4 nk0, nk1, nv0, nv1;
        if (tile + 1 < ATTN_TILES) {
            const size_t n0n = chunk_base + (size_t)(tile + 1) * 64;
            const uint4* ksrc = (const uint4*)&kv[(n0n + n_loc) * 128 + sub * 16];
            nk0 = ksrc[0]; nk1 = ksrc[1];
            const uint4* vsrc = (const uint4*)&kv[(n0n + (t >> 2)) * 128 + 64 + (t & 3) * 16];
            nv0 = vsrc[0]; nv1 = vsrc[1];
        }

        // phase A: logits (4 subs x 16 h each)
        float part[K_SLOTS];
        #pragma unroll
        for (int k = 0; k < K_SLOTS; ++k) {
            const float4* q4p = (const float4*)&q_lds[k * 64 + sub * 16];
            const float4 qa = q4p[0], qb4 = q4p[1], qc = q4p[2], qd = q4p[3];
            part[k] = qa.x * kf[0]  + qa.y * kf[1]  + qa.z * kf[2]  + qa.w * kf[3]
                    + qb4.x * kf[4] + qb4.y * kf[5] + qb4.z * kf[6] + qb4.w * kf[7]
                    + qc.x * kf[8]  + qc.y * kf[9]  + qc.z * kf[10] + qc.w * kf[11]
                    + qd.x * kf[12] + qd.y * kf[13] + qd.z * kf[14] + qd.w * kf[15];
        }

        #pragma unroll
        for (int k = 0; k < K_SLOTS; ++k) {
            part[k] += __shfl_xor(part[k], 1, 64);
            part[k] += __shfl_xor(part[k], 2, 64);
        }
        float mx = part[0];
        #pragma unroll
        for (int k = 1; k < K_SLOTS; ++k) mx = fmaxf(mx, part[k]);
        float e[K_SLOTS], ssum = 0.f;
        #pragma unroll
        for (int k = 0; k < K_SLOTS; ++k) { e[k] = __expf(part[k] - mx); ssum += e[k]; }
        const float rs = 1.0f / ssum;
        if (sub == 0) {
            #pragma unroll
            for (int k = 0; k < K_SLOTS; ++k) {
                const float p = e[k] * rs;
                p_lds[k][n_loc] = p;
                Sacc[k] += p;
            }
        }
        __syncthreads();

        // phase B: U[k][h] partial over this wave's 16 n
        float vf[16];
        #pragma unroll
        for (int i = 0; i < 16; ++i) vf[i] = (float)Vt[w * 16 + i][h];
        #pragma unroll
        for (int k = 0; k < K_SLOTS; ++k) {
            const float4* pp = (const float4*)&p_lds[k][w * 16];
            const float4 p0 = pp[0], p1 = pp[1], p2 = pp[2], p3 = pp[3];
            Uacc[k] += p0.x * vf[0]  + p0.y * vf[1]  + p0.z * vf[2]  + p0.w * vf[3]
                     + p1.x * vf[4]  + p1.y * vf[5]  + p1.z * vf[6]  + p1.w * vf[7]
                     + p2.x * vf[8]  + p2.y * vf[9]  + p2.z * vf[10] + p2.w * vf[11]
                     + p3.x * vf[12] + p3.y * vf[13] + p3.z * vf[14] + p3.w * vf[15];
        }

        k0 = nk0; k1 = nk1; v0 = nv0; v1 = nv1;
    }

    #pragma unroll
    for (int k = 0; k < K_SLOTS; ++k) U_red[w][k][h] = Uacc[k];
    #pragma unroll
    for (int k = 0; k < K_SLOTS; ++k) {
        const float s = wave_reduce_sum(Sacc[k]);
        if (lane == 0) S_red[w][k] = s;
    }
    __syncthreads();
    for (int idx = t; idx < K_SLOTS * 64; idx += 256) {
        const int k = idx >> 6, hh = idx & 63;
        const float s = U_red[0][k][hh] + U_red[1][k][hh] + U_red[2][k][hh] + U_red[3][k][hh];
        U_part[(((size_t)b * CHUNKS + chunk) * K_SLOTS + k) * 64 + hh] = s;
    }
    if (t < K_SLOTS) {
        const float s = S_red[0][t] + S_red[1][t] + S_red[2][t] + S_red[3][t];
        S_part[((size_t)b * CHUNKS + chunk) * K_SLOTS + t] = s;
    }
}

// ================= update: 256 threads/block, 4-way j-split per GEMV phase ==========
// Each wave computes a 16-wide j-slice of every dot product (u/hp broadcast via
// wave-local shfl), partials combined through small LDS reductions. Serial chain
// per phase: 16 loads instead of 64; 4x the waves to hide the rest.
__global__ __launch_bounds__(256) void update_kernel(
    const float* __restrict__ U_part, const float* __restrict__ S_part,
    float* __restrict__ slots,
    const float* __restrict__ WihT, const float* __restrict__ WhhT,
    const float* __restrict__ b_ih, const float* __restrict__ b_hh,
    const float* __restrict__ g_mlp, const float* __restrict__ b_mlp,
    const float* __restrict__ W1T, const float* __restrict__ b1,
    const float* __restrict__ W2T, const float* __restrict__ b2,
    const float* __restrict__ g_slot, const float* __restrict__ b_slot,
    const float* __restrict__ WqT, float* __restrict__ qb,
    float* __restrict__ out, int last)
{
    __shared__ float g_red[4][6][64];
    __shared__ float m_red[4][2][64];
    __shared__ float o_red[4][64];
    __shared__ float q_red[4][64];

    const int t = threadIdx.x;
    const int lane = t & 63;
    const int w = t >> 6;
    const int bk = blockIdx.x;
    const int b = bk / K_SLOTS, k = bk % K_SLOTS;

    // u, hp computed redundantly per wave (all loads L2-resident, fully parallel)
    float Us = 0.f, Ss = 0.f;
    #pragma unroll
    for (int c = 0; c < CHUNKS; ++c) {
        Us += U_part[(((size_t)b * CHUNKS + c) * K_SLOTS + k) * 64 + lane];
        Ss += S_part[((size_t)b * CHUNKS + c) * K_SLOTS + k];
    }
    const float u = Us / (Ss + 1e-8f);
    const float hp = slots[bk * 64 + lane];

    // ---- GRU partials: wave w covers j in [16w, 16w+16) ----
    float pr0 = 0.f, pr1 = 0.f, pr2 = 0.f, pr3 = 0.f, pr4 = 0.f, pr5 = 0.f;
    #pragma unroll
    for (int jj = 0; jj < 16; ++jj) {
        const int j = w * 16 + jj;
        const float xj = __shfl(u, j, 64);
        const float hj = __shfl(hp, j, 64);
        const float* wi = &WihT[j * 192];
        const float* wh = &WhhT[j * 192];
        pr0 += wi[lane] * xj; pr1 += wi[64 + lane] * xj; pr2 += wi[128 + lane] * xj;
        pr3 += wh[lane] * hj; pr4 += wh[64 + lane] * hj; pr5 += wh[128 + lane] * hj;
    }
    g_red[w][0][lane] = pr0; g_red[w][1][lane] = pr1; g_red[w][2][lane] = pr2;
    g_red[w][3][lane] = pr3; g_red[w][4][lane] = pr4; g_red[w][5][lane] = pr5;
    __syncthreads();

    float ir = b_ih[lane], iz = b_ih[64 + lane], inn = b_ih[128 + lane];
    float hr = b_hh[lane], hz = b_hh[64 + lane], hn = b_hh[128 + lane];
    #pragma unroll
    for (int ww = 0; ww < 4; ++ww) {
        ir += g_red[ww][0][lane]; iz += g_red[ww][1][lane]; inn += g_red[ww][2][lane];
        hr += g_red[ww][3][lane]; hz += g_red[ww][4][lane]; hn += g_red[ww][5][lane];
    }
    const float r = 1.0f / (1.0f + __expf(-(ir + hr)));
    const float z = 1.0f / (1.0f + __expf(-(iz + hz)));
    const float nn = tanhf(inn + r * hn);
    const float hnew = (1.0f - z) * nn + z * hp;

    // ---- LN (identical redundant computation in every wave) ----
    const float s1 = wave_reduce_sum(hnew);
    const float s2 = wave_reduce_sum(hnew * hnew);
    const float m = s1 * (1.0f / 64.0f);
    const float inv = rsqrtf(s2 * (1.0f / 64.0f) - m * m + 1e-5f);
    const float mv = (hnew - m) * inv * g_mlp[lane] + b_mlp[lane];

    // ---- MLP1 partials: wave w covers j in [16w, 16w+16) ----
    float a1 = 0.f, a2 = 0.f;
    #pragma unroll
    for (int jj = 0; jj < 16; ++jj) {
        const int j = w * 16 + jj;
        const float mj = __shfl(mv, j, 64);
        a1 += W1T[j * 128 + lane] * mj;
        a2 += W1T[j * 128 + 64 + lane] * mj;
    }
    m_red[w][0][lane] = a1; m_red[w][1][lane] = a2;
    __syncthreads();

    float f1 = b1[lane], f2 = b1[64 + lane];
    #pragma unroll
    for (int ww = 0; ww < 4; ++ww) { f1 += m_red[ww][0][lane]; f2 += m_red[ww][1][lane]; }
    const float r1 = fmaxf(f1, 0.f), r2 = fmaxf(f2, 0.f);

    // ---- MLP2 partials: wave w covers c in [32w, 32w+32) (wave-uniform r1/r2 pick) ----
    float op = 0.f;
    #pragma unroll
    for (int cc = 0; cc < 32; ++cc) {
        const int c = w * 32 + cc;
        const float rc = (c < 64) ? __shfl(r1, c, 64) : __shfl(r2, c - 64, 64);
        op += W2T[c * 64 + lane] * rc;
    }
    o_red[w][lane] = op;
    __syncthreads();

    float o = b2[lane];
    #pragma unroll
    for (int ww = 0; ww < 4; ++ww) o += o_red[ww][lane];
    const float res = hnew + o;

    if (w == 0) {
        slots[bk * 64 + lane] = res;
        if (last) out[bk * 64 + lane] = res;
    }

    if (!last) {
        // ---- fused q for next iteration: 4-way j-split ----
        const float t1 = wave_reduce_sum(res);
        const float t2 = wave_reduce_sum(res * res);
        const float mm = t1 * (1.0f / 64.0f);
        const float ii = rsqrtf(t2 * (1.0f / 64.0f) - mm * mm + 1e-5f);
        const float mq = (res - mm) * ii * g_slot[lane] + b_slot[lane];
        float qp = 0.f;
        #pragma unroll
        for (int jj = 0; jj < 16; ++jj) {
            const int j = w * 16 + jj;
            qp += WqT[j * 64 + lane] * __shfl(mq, j, 64);
        }
        q_red[w][lane] = qp;
        __syncthreads();
        if (w == 0) {
            qb[bk * 64 + lane] = q_red[0][lane] + q_red[1][lane] + q_red[2][lane] + q_red[3][lane];
        }
    }
}

extern "C" void kernel_launch(void* const* d_in, const int* in_sizes, int n_in,
                              void* d_out, int out_size, void* d_ws, size_t ws_size,
                              hipStream_t stream) {
    const float* feat      = (const float*)d_in[0];
    const float* noise     = (const float*)d_in[1];
    const float* mu        = (const float*)d_in[2];
    const float* sigma     = (const float*)d_in[3];
    const float* ln_feat_g = (const float*)d_in[4];
    const float* ln_feat_b = (const float*)d_in[5];
    const float* ln_slot_g = (const float*)d_in[6];
    const float* ln_slot_b = (const float*)d_in[7];
    const float* ln_mlp_g  = (const float*)d_in[8];
    const float* ln_mlp_b  = (const float*)d_in[9];
    const float* Wk        = (const float*)d_in[10];
    const float* Wv        = (const float*)d_in[11];
    const float* Wq        = (const float*)d_in[12];
    const float* W_ih      = (const float*)d_in[13];
    const float* W_hh      = (const float*)d_in[14];
    const float* b_ih      = (const float*)d_in[15];
    const float* b_hh      = (const float*)d_in[16];
    const float* W1        = (const float*)d_in[17];
    const float* b1        = (const float*)d_in[18];
    const float* W2        = (const float*)d_in[19];
    const float* b2        = (const float*)d_in[20];
    float* out = (float*)d_out;

    char* p = (char*)d_ws;
    __bf16* kv    = (__bf16*)p;                 p += (size_t)B_SZ * N_TOK * 128 * 2;  // 64 MB
    __bf16* Wfrag = (__bf16*)p;                 p += 32768 * 2;
    float* slots  = (float*)p;                  p += 24576 * 4;
    float* qb     = (float*)p;                  p += 24576 * 4;
    float* U_part = (float*)p;                  p += (size_t)B_SZ * CHUNKS * K_SLOTS * 64 * 4;
    float* S_part = (float*)p;                  p += (size_t)B_SZ * CHUNKS * K_SLOTS * 4;
    float* WqT    = (float*)p;                  p += 4096 * 4;
    float* WihT   = (float*)p;                  p += 12288 * 4;
    float* WhhT   = (float*)p;                  p += 12288 * 4;
    float* W1T    = (float*)p;                  p += 8192 * 4;
    float* W2T    = (float*)p;                  p += 8192 * 4;

    hipLaunchKernelGGL(prep_kernel, dim3(288), dim3(256), 0, stream,
                       Wk, Wv, noise, mu, sigma, Wq, W_ih, W_hh, W1, W2,
                       Wfrag, slots, WqT, WihT, WhhT, W1T, W2T);
    hipLaunchKernelGGL(ln_kv_mfma, dim3(LNKV_BLOCKS), dim3(256), 0, stream,
                       feat, ln_feat_g, ln_feat_b, Wfrag, kv);
    hipLaunchKernelGGL(slot_q0, dim3(384), dim3(64), 0, stream,
                       slots, ln_slot_g, ln_slot_b, WqT, qb);
    for (int it = 0; it < N_IT; ++it) {
        hipLaunchKernelGGL(attn_kernel, dim3(CHUNKS, B_SZ), dim3(256), 0, stream,
                           qb, kv, U_part, S_part);
        hipLaunchKernelGGL(update_kernel, dim3(384), dim3(256), 0, stream,
                           U_part, S_part, slots, WihT, WhhT, b_ih, b_hh,
                           ln_mlp_g, ln_mlp_b, W1T, b1, W2T, b2,
                           ln_slot_g, ln_slot_b, WqT, qb,
                           out, (it == N_IT - 1) ? 1 : 0);
    }
}

// Round 7
// 498.201 us; speedup vs baseline: 1.4622x; 1.0076x over previous
//
#include <hip/hip_runtime.h>
#include <hip/hip_bf16.h>
#include <math.h>

#define B_SZ    64
#define N_TOK   4096
#define D_FEAT  256
#define K_SLOTS 6
#define H_DIM   64
#define N_IT    3
#define CHUNKS  16
#define ATTN_TILES ((N_TOK / CHUNKS) / 64)   // 4
#define LNKV_BLOCKS 512
#define TILES_PER_BLOCK 8   // 512 blocks * 8 tiles * 64 rows = 262144 rows

typedef __attribute__((ext_vector_type(8))) __bf16 bf16x8;
typedef __attribute__((ext_vector_type(4))) __bf16 bf16x4;
typedef __attribute__((ext_vector_type(4))) float  f32x4v;

__device__ __forceinline__ float wave_reduce_sum(float v) {
    #pragma unroll
    for (int off = 32; off > 0; off >>= 1) v += __shfl_xor(v, off, 64);
    return v;
}
__device__ __forceinline__ float bflo(unsigned u) { return __builtin_bit_cast(float, (unsigned)(u << 16)); }
__device__ __forceinline__ float bfhi(unsigned u) { return __builtin_bit_cast(float, (unsigned)(u & 0xffff0000u)); }

// Barrier that waits only on LDS ops (lgkmcnt), NOT on outstanding global loads
// (vmcnt). __syncthreads() drains vmcnt(0), killing cross-barrier prefetch.
// Valid whenever the barrier guards LDS-only hazards (argued per-hazard at each
// use site). Single asm block with memory clobber => no memory op crosses it.
__device__ __forceinline__ void lgkm_barrier() {
    asm volatile("s_waitcnt lgkmcnt(0)\n\ts_barrier" ::: "memory");
}

// ================= prep: W->bf16 fragment order, slots init, transposed small weights ==========
__global__ __launch_bounds__(256) void prep_kernel(
    const float* __restrict__ Wk, const float* __restrict__ Wv,
    const float* __restrict__ noise, const float* __restrict__ mu,
    const float* __restrict__ sigma, const float* __restrict__ Wq,
    const float* __restrict__ W_ih, const float* __restrict__ W_hh,
    const float* __restrict__ W1, const float* __restrict__ W2,
    __bf16* __restrict__ Wfrag, float* __restrict__ slots,
    float* __restrict__ WqT, float* __restrict__ WihT, float* __restrict__ WhhT,
    float* __restrict__ W1T, float* __restrict__ W2T)
{
    const int tg = blockIdx.x * 256 + threadIdx.x;
    if (tg < 4096) {
        // W fragment order: [ct][ks][lane][j], value = Wkv[ct*16+(lane&15)][(lane>>4)*8+ks*32+j]
        const int chunk = tg >> 6, lane = tg & 63;
        const int ct = chunk >> 3, ks = chunk & 7;
        const int outr = ct * 16 + (lane & 15);
        const int dbase = (lane >> 4) * 8 + ks * 32;
        const float* srcw = (outr < 64) ? &Wk[outr * 256] : &Wv[(outr - 64) * 256];
        bf16x8 w8;
        #pragma unroll
        for (int j = 0; j < 8; ++j) w8[j] = (__bf16)srcw[dbase + j];
        *(bf16x8*)&Wfrag[(size_t)tg * 8] = w8;
    } else if (tg < 4096 + 24576) {
        const int i = tg - 4096;
        const int hh = i & 63;
        slots[i] = mu[hh] + sigma[hh] * noise[i];
    } else if (tg < 32768) {
        const int i = tg - 28672;                 // WqT[j*64+h] = Wq[h*64+j]
        WqT[i] = Wq[(i & 63) * 64 + (i >> 6)];
    } else if (tg < 45056) {
        const int i = tg - 32768;                 // WihT[j*192+r] = W_ih[r*64+j]
        WihT[i] = W_ih[(i % 192) * 64 + (i / 192)];
    } else if (tg < 57344) {
        const int i = tg - 45056;
        WhhT[i] = W_hh[(i % 192) * 64 + (i / 192)];
    } else if (tg < 65536) {
        const int i = tg - 57344;                 // W1T[j*128+r] = W1[r*64+j]
        W1T[i] = W1[(i & 127) * 64 + (i >> 7)];
    } else if (tg < 73728) {
        const int i = tg - 65536;                 // W2T[c*64+h] = W2[h*128+c]
        W2T[i] = W2[(i & 63) * 128 + (i >> 6)];
    }
}

// ================= Stage 1: fused LN + MFMA GEMM -> kv bf16 [row][128] ==========
// Barriers are lgkm-only so the next-tile feat prefetch stays in flight across
// them. Hazard check: A_lds write(t+1) vs read(t) separated by barrier2(t);
// C_lds write(t+1) vs store-read(t) separated by barrier1(t+1); both DS-only.
__global__ __launch_bounds__(256, 2) void ln_kv_mfma(
    const float* __restrict__ feat, const float* __restrict__ g,
    const float* __restrict__ bta, const __bf16* __restrict__ Wfrag,
    __bf16* __restrict__ kv)
{
    __shared__ __align__(16) __bf16 A_lds[64][264];    // 33.8 KB
    __shared__ __align__(16) __bf16 C_lds[64][136];    // 17.4 KB

    const int t = threadIdx.x;
    const int lane = t & 63;
    const int w = t >> 6;
    const int m15 = lane & 15;
    const int q4 = lane >> 4;

    // W fragments in registers: wave w owns ct = 2w, 2w+1 (16 frags = 64 VGPRs)
    bf16x8 wf[2][8];
    #pragma unroll
    for (int c2 = 0; c2 < 2; ++c2)
        #pragma unroll
        for (int ks = 0; ks < 8; ++ks)
            wf[c2][ks] = *(const bf16x8*)&Wfrag[(size_t)(((2 * w + c2) * 8 + ks) * 64 + lane) * 8];

    const float4 gg = *(const float4*)&g[lane * 4];
    const float4 bb = *(const float4*)&bta[lane * 4];

    float4 x[16];
    {   // prefetch tile 0 (wave-private rows)
        const size_t row0 = (size_t)blockIdx.x * TILES_PER_BLOCK * 64 + w * 16;
        #pragma unroll
        for (int r = 0; r < 16; ++r)
            x[r] = *(const float4*)&feat[(row0 + r) * D_FEAT + lane * 4];
    }

    for (int tile = 0; tile < TILES_PER_BLOCK; ++tile) {
        const size_t tile_row0 = (size_t)blockIdx.x * TILES_PER_BLOCK * 64 + (size_t)tile * 64;

        // ---- LN: batched stats, 32 independent reduction trees ----
        float s1[16], s2[16];
        #pragma unroll
        for (int r = 0; r < 16; ++r) {
            s1[r] = x[r].x + x[r].y + x[r].z + x[r].w;
            s2[r] = x[r].x * x[r].x + x[r].y * x[r].y + x[r].z * x[r].z + x[r].w * x[r].w;
        }
        #pragma unroll
        for (int off = 32; off > 0; off >>= 1) {
            #pragma unroll
            for (int r = 0; r < 16; ++r) {
                s1[r] += __shfl_xor(s1[r], off, 64);
                s2[r] += __shfl_xor(s2[r], off, 64);
            }
        }
        #pragma unroll
        for (int r = 0; r < 16; ++r) {
            const float m = s1[r] * (1.0f / 256.0f);
            const float inv = rsqrtf(s2[r] * (1.0f / 256.0f) - m * m + 1e-5f);
            bf16x4 y;
            y[0] = (__bf16)((x[r].x - m) * inv * gg.x + bb.x);
            y[1] = (__bf16)((x[r].y - m) * inv * gg.y + bb.y);
            y[2] = (__bf16)((x[r].z - m) * inv * gg.z + bb.z);
            y[3] = (__bf16)((x[r].w - m) * inv * gg.w + bb.w);
            *(bf16x4*)&A_lds[w * 16 + r][lane * 4] = y;
        }

        // prefetch next tile; with lgkm-only barriers this stays in flight
        // through barrier1 + MFMA + barrier2, hiding HBM latency fully
        if (tile + 1 < TILES_PER_BLOCK) {
            const size_t row0 = tile_row0 + 64 + w * 16;
            #pragma unroll
            for (int r = 0; r < 16; ++r)
                x[r] = *(const float4*)&feat[(row0 + r) * D_FEAT + lane * 4];
        }

        lgkm_barrier();   // A_lds ready (DS-only hazard; do NOT drain vmcnt)

        // ---- MFMA: 4 m-tiles x 2 owned col-tiles, W from registers ----
        f32x4v acc[4][2];
        #pragma unroll
        for (int mt = 0; mt < 4; ++mt) {
            acc[mt][0] = (f32x4v){0.f, 0.f, 0.f, 0.f};
            acc[mt][1] = (f32x4v){0.f, 0.f, 0.f, 0.f};
        }
        #pragma unroll
        for (int ks = 0; ks < 8; ++ks) {
            #pragma unroll
            for (int mt = 0; mt < 4; ++mt) {
                const bf16x8 af = *(const bf16x8*)&A_lds[mt * 16 + m15][q4 * 8 + ks * 32];
                acc[mt][0] = __builtin_amdgcn_mfma_f32_16x16x32_bf16(af, wf[0][ks], acc[mt][0], 0, 0, 0);
                acc[mt][1] = __builtin_amdgcn_mfma_f32_16x16x32_bf16(af, wf[1][ks], acc[mt][1], 0, 0, 0);
            }
        }

        // repack: this wave's 32 cols, all 64 rows
        #pragma unroll
        for (int mt = 0; mt < 4; ++mt)
            #pragma unroll
            for (int c2 = 0; c2 < 2; ++c2)
                #pragma unroll
                for (int reg = 0; reg < 4; ++reg)
                    C_lds[mt * 16 + q4 * 4 + reg][(2 * w + c2) * 16 + m15] = (__bf16)acc[mt][c2][reg];

        lgkm_barrier();   // C_lds complete (DS-only hazard)

        // coalesced bf16 store: wave w stores rows w*16..+15
        const int lr = w * 16 + (lane >> 2);
        const int seg = lane & 3;
        __bf16* dstg = kv + (tile_row0 + lr) * 128 + seg * 32;
        #pragma unroll
        for (int u = 0; u < 4; ++u) {
            const uint4 val = *(const uint4*)&C_lds[lr][seg * 32 + u * 8];
            *(uint4*)&dstg[u * 8] = val;
        }
    }
}

// ================= initial q from slots: 256 threads, 4-way j-split ==========
__global__ __launch_bounds__(256) void slot_q0(
    const float* __restrict__ slots, const float* __restrict__ g,
    const float* __restrict__ bta, const float* __restrict__ WqT,
    float* __restrict__ qb)
{
    __shared__ float q_red[4][64];
    const int bk = blockIdx.x, t = threadIdx.x;
    const int lane = t & 63, w = t >> 6;
    const float xv = slots[bk * 64 + lane];
    const float s1 = wave_reduce_sum(xv);
    const float s2 = wave_reduce_sum(xv * xv);
    const float m = s1 * (1.0f / 64.0f);
    const float inv = rsqrtf(s2 * (1.0f / 64.0f) - m * m + 1e-5f);
    const float sv = (xv - m) * inv * g[lane] + bta[lane];
    float qp = 0.f;
    #pragma unroll
    for (int jj = 0; jj < 16; ++jj) {
        const int j = w * 16 + jj;
        qp += WqT[j * 64 + lane] * __shfl(sv, j, 64);
    }
    q_red[w][lane] = qp;
    __syncthreads();
    if (w == 0)
        qb[bk * 64 + lane] = q_red[0][lane] + q_red[1][lane] + q_red[2][lane] + q_red[3][lane];
}

// ================= attention: 1024 blocks (4/CU), lgkm barriers + cross-tile prefetch ====
// Barriers guard q_lds/Vt/p_lds (DS-only). Prefetched k/v loads stay in flight
// across both barriers of the next tile.
__global__ __launch_bounds__(256, 4) void attn_kernel(
    const float* __restrict__ qb, const __bf16* __restrict__ kv,
    float* __restrict__ U_part, float* __restrict__ S_part)
{
    __shared__ float q_lds[K_SLOTS * 64];
    __shared__ __align__(16) __bf16 Vt[64][64];   // raw bf16, row n, col h
    __shared__ float p_lds[K_SLOTS][64];
    __shared__ float U_red[4][K_SLOTS][64];
    __shared__ float S_red[4][K_SLOTS];

    const int t = threadIdx.x;
    const int b = blockIdx.y;
    const int chunk = blockIdx.x;
    const int lane = t & 63;
    const int w = t >> 6;
    const int n_loc = t >> 2, sub = t & 3;
    const int h = lane;

    // q pre-scaled by 1/sqrt(H) once
    for (int i = t; i < K_SLOTS * 64; i += 256) q_lds[i] = qb[b * K_SLOTS * 64 + i] * 0.125f;

    float Uacc[K_SLOTS] = {0, 0, 0, 0, 0, 0};
    float Sacc[K_SLOTS] = {0, 0, 0, 0, 0, 0};

    const size_t chunk_base = (size_t)b * N_TOK + (size_t)chunk * (N_TOK / CHUNKS);

    // prologue: tile-0 k/v loads into registers
    uint4 k0, k1, v0, v1;
    {
        const uint4* ksrc = (const uint4*)&kv[(chunk_base + n_loc) * 128 + sub * 16];
        k0 = ksrc[0]; k1 = ksrc[1];
        const uint4* vsrc = (const uint4*)&kv[(chunk_base + (t >> 2)) * 128 + 64 + (t & 3) * 16];
        v0 = vsrc[0]; v1 = vsrc[1];
    }

    for (int tile = 0; tile < ATTN_TILES; ++tile) {
        lgkm_barrier();   // guard Vt/p_lds reuse (covers q_lds on tile 0); DS-only

        // stage V for this tile (raw bf16)
        *(uint4*)&Vt[t >> 2][(t & 3) * 16] = v0;
        *(uint4*)&Vt[t >> 2][(t & 3) * 16 + 8] = v1;

        float kf[16];
        kf[0]  = bflo(k0.x); kf[1]  = bfhi(k0.x); kf[2]  = bflo(k0.y); kf[3]  = bfhi(k0.y);
        kf[4]  = bflo(k0.z); kf[5]  = bfhi(k0.z); kf[6]  = bflo(k0.w); kf[7]  = bfhi(k0.w);
        kf[8]  = bflo(k1.x); kf[9]  = bfhi(k1.x); kf[10] = bflo(k1.y); kf[11] = bfhi(k1.y);
        kf[12] = bflo(k1.z); kf[13] = bfhi(k1.z); kf[14] = bflo(k1.w); kf[15] = bfhi(k1.w);

        // prefetch next tile's k/v (stays in flight across the next barriers)
        uint4 nk0, nk1, nv0, nv1;
        if (tile + 1 < ATTN_TILES) {
            const size_t n0n = chunk_base + (size_t)(tile + 1) * 64;
            const uint4* ksrc = (const uint4*)&kv[(n0n + n_loc) * 128 + sub * 16];
            nk0 = ksrc[0]; nk1 = ksrc[1];
            const uint4* vsrc = (const uint4*)&kv[(n0n + (t >> 2)) * 128 + 64 + (t & 3) * 16];
            nv0 = vsrc[0]; nv1 = vsrc[1];
        }

        // phase A: logits (4 subs x 16 h each)
        float part[K_SLOTS];
        #pragma unroll
        for (int k = 0; k < K_SLOTS; ++k) {
            const float4* q4p = (const float4*)&q_lds[k * 64 + sub * 16];
            const float4 qa = q4p[0], qb4 = q4p[1], qc = q4p[2], qd = q4p[3];
            part[k] = qa.x * kf[0]  + qa.y * kf[1]  + qa.z * kf[2]  + qa.w * kf[3]
                    + qb4.x * kf[4] + qb4.y * kf[5] + qb4.z * kf[6] + qb4.w * kf[7]
                    + qc.x * kf[8]  + qc.y * kf[9]  + qc.z * kf[10] + qc.w * kf[11]
                    + qd.x * kf[12] + qd.y * kf[13] + qd.z * kf[14] + qd.w * kf[15];
        }

        #pragma unroll
        for (int k = 0; k < K_SLOTS; ++k) {
            part[k] += __shfl_xor(part[k], 1, 64);
            part[k] += __shfl_xor(part[k], 2, 64);
        }
        float mx = part[0];
        #pragma unroll
        for (int k = 1; k < K_SLOTS; ++k) mx = fmaxf(mx, part[k]);
        float e[K_SLOTS], ssum = 0.f;
        #pragma unroll
        for (int k = 0; k < K_SLOTS; ++k) { e[k] = __expf(part[k] - mx); ssum += e[k]; }
        const float rs = 1.0f / ssum;
        if (sub == 0) {
            #pragma unroll
            for (int k = 0; k < K_SLOTS; ++k) {
                const float p = e[k] * rs;
                p_lds[k][n_loc] = p;
                Sacc[k] += p;
            }
        }
        lgkm_barrier();   // Vt + p_lds ready (DS-only)

        // phase B: U[k][h] partial over this wave's 16 n
        float vf[16];
        #pragma unroll
        for (int i = 0; i < 16; ++i) vf[i] = (float)Vt[w * 16 + i][h];
        #pragma unroll
        for (int k = 0; k < K_SLOTS; ++k) {
            const float4* pp = (const float4*)&p_lds[k][w * 16];
            const float4 p0 = pp[0], p1 = pp[1], p2 = pp[2], p3 = pp[3];
            Uacc[k] += p0.x * vf[0]  + p0.y * vf[1]  + p0.z * vf[2]  + p0.w * vf[3]
                     + p1.x * vf[4]  + p1.y * vf[5]  + p1.z * vf[6]  + p1.w * vf[7]
                     + p2.x * vf[8]  + p2.y * vf[9]  + p2.z * vf[10] + p2.w * vf[11]
                     + p3.x * vf[12] + p3.y * vf[13] + p3.z * vf[14] + p3.w * vf[15];
        }

        k0 = nk0; k1 = nk1; v0 = nv0; v1 = nv1;
    }

    #pragma unroll
    for (int k = 0; k < K_SLOTS; ++k) U_red[w][k][h] = Uacc[k];
    #pragma unroll
    for (int k = 0; k < K_SLOTS; ++k) {
        const float s = wave_reduce_sum(Sacc[k]);
        if (lane == 0) S_red[w][k] = s;
    }
    __syncthreads();
    for (int idx = t; idx < K_SLOTS * 64; idx += 256) {
        const int k = idx >> 6, hh = idx & 63;
        const float s = U_red[0][k][hh] + U_red[1][k][hh] + U_red[2][k][hh] + U_red[3][k][hh];
        U_part[(((size_t)b * CHUNKS + chunk) * K_SLOTS + k) * 64 + hh] = s;
    }
    if (t < K_SLOTS) {
        const float s = S_red[0][t] + S_red[1][t] + S_red[2][t] + S_red[3][t];
        S_part[((size_t)b * CHUNKS + chunk) * K_SLOTS + t] = s;
    }
}

// ================= update: 256 threads/block, 4-way j-split per GEMV phase ==========
__global__ __launch_bounds__(256) void update_kernel(
    const float* __restrict__ U_part, const float* __restrict__ S_part,
    float* __restrict__ slots,
    const float* __restrict__ WihT, const float* __restrict__ WhhT,
    const float* __restrict__ b_ih, const float* __restrict__ b_hh,
    const float* __restrict__ g_mlp, const float* __restrict__ b_mlp,
    const float* __restrict__ W1T, const float* __restrict__ b1,
    const float* __restrict__ W2T, const float* __restrict__ b2,
    const float* __restrict__ g_slot, const float* __restrict__ b_slot,
    const float* __restrict__ WqT, float* __restrict__ qb,
    float* __restrict__ out, int last)
{
    __shared__ float g_red[4][6][64];
    __shared__ float m_red[4][2][64];
    __shared__ float o_red[4][64];
    __shared__ float q_red[4][64];

    const int t = threadIdx.x;
    const int lane = t & 63;
    const int w = t >> 6;
    const int bk = blockIdx.x;
    const int b = bk / K_SLOTS, k = bk % K_SLOTS;

    // u, hp computed redundantly per wave (all loads L2-resident, fully parallel)
    float Us = 0.f, Ss = 0.f;
    #pragma unroll
    for (int c = 0; c < CHUNKS; ++c) {
        Us += U_part[(((size_t)b * CHUNKS + c) * K_SLOTS + k) * 64 + lane];
        Ss += S_part[((size_t)b * CHUNKS + c) * K_SLOTS + k];
    }
    const float u = Us / (Ss + 1e-8f);
    const float hp = slots[bk * 64 + lane];

    // ---- GRU partials: wave w covers j in [16w, 16w+16) ----
    float pr0 = 0.f, pr1 = 0.f, pr2 = 0.f, pr3 = 0.f, pr4 = 0.f, pr5 = 0.f;
    #pragma unroll
    for (int jj = 0; jj < 16; ++jj) {
        const int j = w * 16 + jj;
        const float xj = __shfl(u, j, 64);
        const float hj = __shfl(hp, j, 64);
        const float* wi = &WihT[j * 192];
        const float* wh = &WhhT[j * 192];
        pr0 += wi[lane] * xj; pr1 += wi[64 + lane] * xj; pr2 += wi[128 + lane] * xj;
        pr3 += wh[lane] * hj; pr4 += wh[64 + lane] * hj; pr5 += wh[128 + lane] * hj;
    }
    g_red[w][0][lane] = pr0; g_red[w][1][lane] = pr1; g_red[w][2][lane] = pr2;
    g_red[w][3][lane] = pr3; g_red[w][4][lane] = pr4; g_red[w][5][lane] = pr5;
    __syncthreads();

    float ir = b_ih[lane], iz = b_ih[64 + lane], inn = b_ih[128 + lane];
    float hr = b_hh[lane], hz = b_hh[64 + lane], hn = b_hh[128 + lane];
    #pragma unroll
    for (int ww = 0; ww < 4; ++ww) {
        ir += g_red[ww][0][lane]; iz += g_red[ww][1][lane]; inn += g_red[ww][2][lane];
        hr += g_red[ww][3][lane]; hz += g_red[ww][4][lane]; hn += g_red[ww][5][lane];
    }
    const float r = 1.0f / (1.0f + __expf(-(ir + hr)));
    const float z = 1.0f / (1.0f + __expf(-(iz + hz)));
    const float nn = tanhf(inn + r * hn);
    const float hnew = (1.0f - z) * nn + z * hp;

    // ---- LN (identical redundant computation in every wave) ----
    const float s1 = wave_reduce_sum(hnew);
    const float s2 = wave_reduce_sum(hnew * hnew);
    const float m = s1 * (1.0f / 64.0f);
    const float inv = rsqrtf(s2 * (1.0f / 64.0f) - m * m + 1e-5f);
    const float mv = (hnew - m) * inv * g_mlp[lane] + b_mlp[lane];

    // ---- MLP1 partials: wave w covers j in [16w, 16w+16) ----
    float a1 = 0.f, a2 = 0.f;
    #pragma unroll
    for (int jj = 0; jj < 16; ++jj) {
        const int j = w * 16 + jj;
        const float mj = __shfl(mv, j, 64);
        a1 += W1T[j * 128 + lane] * mj;
        a2 += W1T[j * 128 + 64 + lane] * mj;
    }
    m_red[w][0][lane] = a1; m_red[w][1][lane] = a2;
    __syncthreads();

    float f1 = b1[lane], f2 = b1[64 + lane];
    #pragma unroll
    for (int ww = 0; ww < 4; ++ww) { f1 += m_red[ww][0][lane]; f2 += m_red[ww][1][lane]; }
    const float r1 = fmaxf(f1, 0.f), r2 = fmaxf(f2, 0.f);

    // ---- MLP2 partials: wave w covers c in [32w, 32w+32) ----
    float op = 0.f;
    #pragma unroll
    for (int cc = 0; cc < 32; ++cc) {
        const int c = w * 32 + cc;
        const float rc = (c < 64) ? __shfl(r1, c, 64) : __shfl(r2, c - 64, 64);
        op += W2T[c * 64 + lane] * rc;
    }
    o_red[w][lane] = op;
    __syncthreads();

    float o = b2[lane];
    #pragma unroll
    for (int ww = 0; ww < 4; ++ww) o += o_red[ww][lane];
    const float res = hnew + o;

    if (w == 0) {
        slots[bk * 64 + lane] = res;
        if (last) out[bk * 64 + lane] = res;
    }

    if (!last) {
        // ---- fused q for next iteration: 4-way j-split ----
        const float t1 = wave_reduce_sum(res);
        const float t2 = wave_reduce_sum(res * res);
        const float mm = t1 * (1.0f / 64.0f);
        const float ii = rsqrtf(t2 * (1.0f / 64.0f) - mm * mm + 1e-5f);
        const float mq = (res - mm) * ii * g_slot[lane] + b_slot[lane];
        float qp = 0.f;
        #pragma unroll
        for (int jj = 0; jj < 16; ++jj) {
            const int j = w * 16 + jj;
            qp += WqT[j * 64 + lane] * __shfl(mq, j, 64);
        }
        q_red[w][lane] = qp;
        __syncthreads();
        if (w == 0) {
            qb[bk * 64 + lane] = q_red[0][lane] + q_red[1][lane] + q_red[2][lane] + q_red[3][lane];
        }
    }
}

extern "C" void kernel_launch(void* const* d_in, const int* in_sizes, int n_in,
                              void* d_out, int out_size, void* d_ws, size_t ws_size,
                              hipStream_t stream) {
    const float* feat      = (const float*)d_in[0];
    const float* noise     = (const float*)d_in[1];
    const float* mu        = (const float*)d_in[2];
    const float* sigma     = (const float*)d_in[3];
    const float* ln_feat_g = (const float*)d_in[4];
    const float* ln_feat_b = (const float*)d_in[5];
    const float* ln_slot_g = (const float*)d_in[6];
    const float* ln_slot_b = (const float*)d_in[7];
    const float* ln_mlp_g  = (const float*)d_in[8];
    const float* ln_mlp_b  = (const float*)d_in[9];
    const float* Wk        = (const float*)d_in[10];
    const float* Wv        = (const float*)d_in[11];
    const float* Wq        = (const float*)d_in[12];
    const float* W_ih      = (const float*)d_in[13];
    const float* W_hh      = (const float*)d_in[14];
    const float* b_ih      = (const float*)d_in[15];
    const float* b_hh      = (const float*)d_in[16];
    const float* W1        = (const float*)d_in[17];
    const float* b1        = (const float*)d_in[18];
    const float* W2        = (const float*)d_in[19];
    const float* b2        = (const float*)d_in[20];
    float* out = (float*)d_out;

    char* p = (char*)d_ws;
    __bf16* kv    = (__bf16*)p;                 p += (size_t)B_SZ * N_TOK * 128 * 2;  // 64 MB
    __bf16* Wfrag = (__bf16*)p;                 p += 32768 * 2;
    float* slots  = (float*)p;                  p += 24576 * 4;
    float* qb     = (float*)p;                  p += 24576 * 4;
    float* U_part = (float*)p;                  p += (size_t)B_SZ * CHUNKS * K_SLOTS * 64 * 4;
    float* S_part = (float*)p;                  p += (size_t)B_SZ * CHUNKS * K_SLOTS * 4;
    float* WqT    = (float*)p;                  p += 4096 * 4;
    float* WihT   = (float*)p;                  p += 12288 * 4;
    float* WhhT   = (float*)p;                  p += 12288 * 4;
    float* W1T    = (float*)p;                  p += 8192 * 4;
    float* W2T    = (float*)p;                  p += 8192 * 4;

    hipLaunchKernelGGL(prep_kernel, dim3(288), dim3(256), 0, stream,
                       Wk, Wv, noise, mu, sigma, Wq, W_ih, W_hh, W1, W2,
                       Wfrag, slots, WqT, WihT, WhhT, W1T, W2T);
    hipLaunchKernelGGL(ln_kv_mfma, dim3(LNKV_BLOCKS), dim3(256), 0, stream,
                       feat, ln_feat_g, ln_feat_b, Wfrag, kv);
    hipLaunchKernelGGL(slot_q0, dim3(384), dim3(256), 0, stream,
                       slots, ln_slot_g, ln_slot_b, WqT, qb);
    for (int it = 0; it < N_IT; ++it) {
        hipLaunchKernelGGL(attn_kernel, dim3(CHUNKS, B_SZ), dim3(256), 0, stream,
                           qb, kv, U_part, S_part);
        hipLaunchKernelGGL(update_kernel, dim3(384), dim3(256), 0, stream,
                           U_part, S_part, slots, WihT, WhhT, b_ih, b_hh,
                           ln_mlp_g, ln_mlp_b, W1T, b1, W2T, b2,
                           ln_slot_g, ln_slot_b, WqT, qb,
                           out, (it == N_IT - 1) ? 1 : 0);
    }
}